// Round 4
// baseline (644.909 us; speedup 1.0000x reference)
//
#include <hip/hip_runtime.h>
#include <hip/hip_bf16.h>
#include <math.h>

#define B 64
#define S 1024
#define D 1024
#define C 10
#define TD 3072  // 3*D
#define NBLK 128 // blocks in fused kernel

typedef __attribute__((ext_vector_type(8))) short s8v;   // 8 bf16 (A/B frag)
typedef __attribute__((ext_vector_type(4))) float f4v;   // 4 f32  (C/D frag)

__device__ __forceinline__ float wave_sum_bc(float v) {
    #pragma unroll
    for (int off = 1; off < 64; off <<= 1) v += __shfl_xor(v, off, 64);
    return v;
}
__device__ __forceinline__ float sigm(float x) { return 1.0f / (1.0f + expf(-x)); }
__device__ __forceinline__ short f2bf(float f) {
    __hip_bfloat16 h = __float2bfloat16(f);
    return *reinterpret_cast<short*>(&h);
}

// ---------------------------------------------------------------------------
// Device-scope grid barrier (generation-based). bar[0]=cnt, bar[1]=gen.
// k_pre zeroes bar[] each launch, so replays are deterministic.
__device__ __forceinline__ void grid_sync(unsigned* bar) {
    __syncthreads();
    if (threadIdx.x == 0) {
        unsigned g = __hip_atomic_load(&bar[1], __ATOMIC_RELAXED, __HIP_MEMORY_SCOPE_AGENT);
        __threadfence();  // release our block's prior global writes
        unsigned arrived = __hip_atomic_fetch_add(&bar[0], 1u, __ATOMIC_ACQ_REL,
                                                  __HIP_MEMORY_SCOPE_AGENT);
        if (arrived == NBLK - 1) {
            __hip_atomic_store(&bar[0], 0u, __ATOMIC_RELAXED, __HIP_MEMORY_SCOPE_AGENT);
            __hip_atomic_store(&bar[1], g + 1u, __ATOMIC_RELEASE, __HIP_MEMORY_SCOPE_AGENT);
        } else {
            while (__hip_atomic_load(&bar[1], __ATOMIC_ACQUIRE, __HIP_MEMORY_SCOPE_AGENT) == g)
                __builtin_amdgcn_s_sleep(8);
        }
        __threadfence();  // acquire: invalidate stale cached lines
    }
    __syncthreads();
}

// ---------------------------------------------------------------------------
// k_pre: block-role merged prologue.
//   [0,1024)      online-softmax pooling partials over feat
//   [1024,2560)   pack W_ih  -> bf16 B-fragments (stride D+1)
//   [2560,4096)   pack W_hh  -> bf16 B-fragments (stride D)
//   [4096,4108)   wscore extraction (+ barrier zeroing on block 4096)
__global__ __launch_bounds__(256) void k_pre(const float* __restrict__ feat,
        const float* __restrict__ a_w, const float* __restrict__ W_ih,
        const float* __restrict__ W_hh, float* __restrict__ part, float* __restrict__ ml,
        short* __restrict__ BihP, short* __restrict__ BhhP, float* __restrict__ wscore,
        unsigned* __restrict__ bar) {
    __shared__ float sacc[4][1024];
    __shared__ float sml[4][2];
    int n = blockIdx.x, tid = threadIdx.x;

    if (n >= 1024) {
        if (n < 4096) {  // pack W
            int rel = n - 1024;
            const float* Wsrc = (rel < 1536) ? W_ih : W_hh;
            short* dst = (rel < 1536) ? BihP : BhhP;
            int stride = (rel < 1536) ? (D + 1) : D;
            int rn = (rel < 1536) ? rel : rel - 1536;
            int gid = rn * 256 + tid;
            int fid = gid >> 6, l = gid & 63;
            int s = fid & 31, g = (fid >> 5) % 3, dt = fid / 96;
            int row = g * 1024 + dt * 16 + (l & 15);
            int k0 = s * 32 + ((l >> 4) << 3);
            const float* src = Wsrc + (size_t)row * stride + k0;
            short v[8];
            #pragma unroll
            for (int j = 0; j < 8; ++j) v[j] = f2bf(src[j]);
            short* d = dst + ((size_t)fid * 64 + l) * 8;
            #pragma unroll
            for (int j = 0; j < 8; ++j) d[j] = v[j];
        } else {  // wscore + barrier init
            int j = (n - 4096) * 256 + tid;
            wscore[j] = W_ih[(size_t)j * (D + 1) + D];
            if (n == 4096 && tid < 8) bar[tid] = 0u;
        }
        return;
    }

    // --- pooling partials (ch = n & 15, b = n >> 4) ---
    int ch = n & 15, b = n >> 4;
    int w = tid >> 6, lane = tid & 63;
    float4 aw[4], acc[4];
    #pragma unroll
    for (int r = 0; r < 4; ++r) {
        aw[r] = *reinterpret_cast<const float4*>(&a_w[r * 256 + lane * 4]);
        acc[r] = make_float4(0.f, 0.f, 0.f, 0.f);
    }
    float m = -INFINITY, l = 0.f;
    const float* fb = feat + ((size_t)b * S + ch * 64 + w * 16) * D;
    for (int i = 0; i < 16; ++i) {
        float4 f[4];
        #pragma unroll
        for (int r = 0; r < 4; ++r)
            f[r] = *reinterpret_cast<const float4*>(&fb[(size_t)i * D + r * 256 + lane * 4]);
        float dot = 0.f;
        #pragma unroll
        for (int r = 0; r < 4; ++r)
            dot += f[r].x * aw[r].x + f[r].y * aw[r].y + f[r].z * aw[r].z + f[r].w * aw[r].w;
        dot = wave_sum_bc(dot);
        if (dot <= m) {
            float wg = expf(dot - m);
            l += wg;
            #pragma unroll
            for (int r = 0; r < 4; ++r) {
                acc[r].x += wg * f[r].x; acc[r].y += wg * f[r].y;
                acc[r].z += wg * f[r].z; acc[r].w += wg * f[r].w;
            }
        } else {
            float sc = expf(m - dot);
            l = l * sc + 1.f;
            #pragma unroll
            for (int r = 0; r < 4; ++r) {
                acc[r].x = acc[r].x * sc + f[r].x; acc[r].y = acc[r].y * sc + f[r].y;
                acc[r].z = acc[r].z * sc + f[r].z; acc[r].w = acc[r].w * sc + f[r].w;
            }
            m = dot;
        }
    }
    #pragma unroll
    for (int r = 0; r < 4; ++r)
        *reinterpret_cast<float4*>(&sacc[w][r * 256 + lane * 4]) = acc[r];
    if (lane == 0) { sml[w][0] = m; sml[w][1] = l; }
    __syncthreads();
    float m0 = sml[0][0], m1 = sml[1][0], m2 = sml[2][0], m3 = sml[3][0];
    float mg = fmaxf(fmaxf(m0, m1), fmaxf(m2, m3));
    float s0 = expf(m0 - mg), s1 = expf(m1 - mg), s2 = expf(m2 - mg), s3 = expf(m3 - mg);
    int c = tid * 4;
    float4 a0 = *reinterpret_cast<float4*>(&sacc[0][c]);
    float4 a1 = *reinterpret_cast<float4*>(&sacc[1][c]);
    float4 a2 = *reinterpret_cast<float4*>(&sacc[2][c]);
    float4 a3 = *reinterpret_cast<float4*>(&sacc[3][c]);
    float4 o;
    o.x = s0 * a0.x + s1 * a1.x + s2 * a2.x + s3 * a3.x;
    o.y = s0 * a0.y + s1 * a1.y + s2 * a2.y + s3 * a3.y;
    o.z = s0 * a0.z + s1 * a1.z + s2 * a2.z + s3 * a3.z;
    o.w = s0 * a0.w + s1 * a1.w + s2 * a2.w + s3 * a3.w;
    *reinterpret_cast<float4*>(&part[((size_t)b * 16 + ch) * D + c]) = o;
    if (tid == 0) {
        float lg = s0 * sml[0][1] + s1 * sml[1][1] + s2 * sml[2][1] + s3 * sml[3][1];
        ml[(b * 16 + ch) * 2] = mg;
        ml[(b * 16 + ch) * 2 + 1] = lg;
    }
}

// ---------------------------------------------------------------------------
// k_fused: pool-combine+packA -> gi0 GEMM -> 10 GRU steps -> final.
// 128 blocks x 256 threads (co-resident on 256 CUs), grid_sync between phases.
__global__ __launch_bounds__(256, 1) void k_fused(const s8v* __restrict__ BihP,
        const s8v* __restrict__ BhhPv, const float* __restrict__ part,
        const float* __restrict__ ml, short* __restrict__ pooledP,
        short* __restrict__ hp0, short* __restrict__ hp1, float* __restrict__ hf,
        float* __restrict__ gi0, const float* __restrict__ wscore,
        const float* __restrict__ b_ih, const float* __restrict__ b_hh,
        const float* __restrict__ W_out, const float* __restrict__ b_out,
        float* __restrict__ spart, float* __restrict__ out, unsigned* __restrict__ bar) {
    __shared__ float psum[4][32][49];
    __shared__ float sredS[32][8];
    __shared__ float sredO[256];
    int tid = threadIdx.x, w = tid >> 6, l = tid & 63;
    int n = blockIdx.x, xcd = n & 7, i = n >> 3;
    int dt = xcd * 8 + (i & 7), bh = i >> 3;

    // ---- Phase A: pool combine + pack A-fragments (blocks 0..63, b = n) ----
    if (n < 64) {
        int b = n;
        float mg = -INFINITY;
        #pragma unroll
        for (int q = 0; q < 16; ++q) mg = fmaxf(mg, ml[(b * 16 + q) * 2]);
        float denom = 0.f, sc[16];
        #pragma unroll
        for (int q = 0; q < 16; ++q) {
            sc[q] = expf(ml[(b * 16 + q) * 2] - mg);
            denom += sc[q] * ml[(b * 16 + q) * 2 + 1];
        }
        float inv = 1.f / denom;
        int c = tid * 4;
        float4 o = make_float4(0.f, 0.f, 0.f, 0.f);
        #pragma unroll
        for (int q = 0; q < 16; ++q) {
            float4 p = *reinterpret_cast<const float4*>(&part[((size_t)b * 16 + q) * D + c]);
            o.x += sc[q] * p.x; o.y += sc[q] * p.y; o.z += sc[q] * p.z; o.w += sc[q] * p.w;
        }
        float ov[4] = {o.x * inv, o.y * inv, o.z * inv, o.w * inv};
        int m = b >> 4;
        #pragma unroll
        for (int j4 = 0; j4 < 4; ++j4) {
            int d = c + j4;
            int s = d >> 5, lane2 = (b & 15) + (((d >> 3) & 3) << 4), jj = d & 7;
            pooledP[(((size_t)m * 32 + s) * 64 + lane2) * 8 + jj] = f2bf(ov[j4]);
        }
    }
    grid_sync(bar);

    // ---- Phase B: gi0 = pooled @ W_ih^T + b_ih ----
    {
        const s8v* Ap = reinterpret_cast<const s8v*>(pooledP);
        f4v acc[2][3];
        #pragma unroll
        for (int mi = 0; mi < 2; ++mi)
            #pragma unroll
            for (int g = 0; g < 3; ++g) acc[mi][g] = (f4v){0.f, 0.f, 0.f, 0.f};
        #pragma unroll 2
        for (int s8 = 0; s8 < 8; ++s8) {
            int s = w * 8 + s8;
            s8v a0 = Ap[(size_t)((bh * 2 + 0) * 32 + s) * 64 + l];
            s8v a1 = Ap[(size_t)((bh * 2 + 1) * 32 + s) * 64 + l];
            s8v b0 = BihP[(size_t)((dt * 3 + 0) * 32 + s) * 64 + l];
            s8v b1 = BihP[(size_t)((dt * 3 + 1) * 32 + s) * 64 + l];
            s8v b2 = BihP[(size_t)((dt * 3 + 2) * 32 + s) * 64 + l];
            acc[0][0] = __builtin_amdgcn_mfma_f32_16x16x32_bf16(a0, b0, acc[0][0], 0, 0, 0);
            acc[0][1] = __builtin_amdgcn_mfma_f32_16x16x32_bf16(a0, b1, acc[0][1], 0, 0, 0);
            acc[0][2] = __builtin_amdgcn_mfma_f32_16x16x32_bf16(a0, b2, acc[0][2], 0, 0, 0);
            acc[1][0] = __builtin_amdgcn_mfma_f32_16x16x32_bf16(a1, b0, acc[1][0], 0, 0, 0);
            acc[1][1] = __builtin_amdgcn_mfma_f32_16x16x32_bf16(a1, b1, acc[1][1], 0, 0, 0);
            acc[1][2] = __builtin_amdgcn_mfma_f32_16x16x32_bf16(a1, b2, acc[1][2], 0, 0, 0);
        }
        #pragma unroll
        for (int mi = 0; mi < 2; ++mi)
            #pragma unroll
            for (int g = 0; g < 3; ++g)
                #pragma unroll
                for (int r = 0; r < 4; ++r)
                    psum[w][mi * 16 + (l >> 4) * 4 + r][g * 16 + (l & 15)] = acc[mi][g][r];
        __syncthreads();
        int lb = tid & 31, b = bh * 32 + lb;
        #pragma unroll
        for (int pp = 0; pp < 2; ++pp) {
            int ld = (tid >> 5) + pp * 8;
            #pragma unroll
            for (int g = 0; g < 3; ++g) {
                int c48 = g * 16 + ld;
                float v = psum[0][lb][c48] + psum[1][lb][c48] + psum[2][lb][c48] + psum[3][lb][c48];
                int col = g * 1024 + dt * 16 + ld;
                gi0[(size_t)b * TD + col] = v + b_ih[col];
            }
        }
    }
    // gi0 written by this block is exactly what this block reads in the steps;
    // no cross-block dep here, so no grid_sync needed (LDS WAR handled below).

    // ---- Load W_hh B-fragments into registers once (reused all 10 steps) ----
    s8v Bw0[8], Bw1[8], Bw2[8];
    #pragma unroll
    for (int s8 = 0; s8 < 8; ++s8) {
        int s = w * 8 + s8;
        Bw0[s8] = BhhPv[(size_t)((dt * 3 + 0) * 32 + s) * 64 + l];
        Bw1[s8] = BhhPv[(size_t)((dt * 3 + 1) * 32 + s) * 64 + l];
        Bw2[s8] = BhhPv[(size_t)((dt * 3 + 2) * 32 + s) * 64 + l];
    }

    // ---- Phase C: 10 GRU steps ----
    for (int t = 0; t < C; ++t) {
        __syncthreads();  // WAR on psum vs previous phase's reads
        if (t > 0) {
            int lb0 = tid & 31, grp = tid >> 5;
            const float* sp = spart + ((size_t)(t - 1) * B + bh * 32 + lb0) * 64 + grp * 8;
            float sv = 0.f;
            #pragma unroll
            for (int q = 0; q < 8; ++q) sv += sp[q];
            sredS[lb0][grp] = sv;
        }
        f4v acc[2][3];
        #pragma unroll
        for (int mi = 0; mi < 2; ++mi)
            #pragma unroll
            for (int g = 0; g < 3; ++g) acc[mi][g] = (f4v){0.f, 0.f, 0.f, 0.f};
        if (t > 0) {
            const s8v* Ain = reinterpret_cast<const s8v*>((t & 1) ? hp1 : hp0);
            #pragma unroll 2
            for (int s8 = 0; s8 < 8; ++s8) {
                int s = w * 8 + s8;
                s8v a0 = Ain[(size_t)((bh * 2 + 0) * 32 + s) * 64 + l];
                s8v a1 = Ain[(size_t)((bh * 2 + 1) * 32 + s) * 64 + l];
                acc[0][0] = __builtin_amdgcn_mfma_f32_16x16x32_bf16(a0, Bw0[s8], acc[0][0], 0, 0, 0);
                acc[0][1] = __builtin_amdgcn_mfma_f32_16x16x32_bf16(a0, Bw1[s8], acc[0][1], 0, 0, 0);
                acc[0][2] = __builtin_amdgcn_mfma_f32_16x16x32_bf16(a0, Bw2[s8], acc[0][2], 0, 0, 0);
                acc[1][0] = __builtin_amdgcn_mfma_f32_16x16x32_bf16(a1, Bw0[s8], acc[1][0], 0, 0, 0);
                acc[1][1] = __builtin_amdgcn_mfma_f32_16x16x32_bf16(a1, Bw1[s8], acc[1][1], 0, 0, 0);
                acc[1][2] = __builtin_amdgcn_mfma_f32_16x16x32_bf16(a1, Bw2[s8], acc[1][2], 0, 0, 0);
            }
        }
        #pragma unroll
        for (int mi = 0; mi < 2; ++mi)
            #pragma unroll
            for (int g = 0; g < 3; ++g)
                #pragma unroll
                for (int r = 0; r < 4; ++r)
                    psum[w][mi * 16 + (l >> 4) * 4 + r][g * 16 + (l & 15)] = acc[mi][g][r];
        __syncthreads();

        int lb = tid & 31, b = bh * 32 + lb;
        float score = 0.f;
        if (t > 0) {
            float ssum = b_out[0];
            #pragma unroll
            for (int g = 0; g < 8; ++g) ssum += sredS[lb][g];
            score = sigm(ssum);
        }
        short* Aout = (t & 1) ? hp0 : hp1;
        float osum = 0.f;
        #pragma unroll
        for (int pp = 0; pp < 2; ++pp) {
            int ld = (tid >> 5) + pp * 8;
            int d = dt * 16 + ld;
            float ghr = b_hh[d], ghz = b_hh[D + d], ghn = b_hh[2 * D + d];
            if (t > 0) {
                #pragma unroll
                for (int ww = 0; ww < 4; ++ww) {
                    ghr += psum[ww][lb][ld];
                    ghz += psum[ww][lb][16 + ld];
                    ghn += psum[ww][lb][32 + ld];
                }
            }
            const float* gb = gi0 + (size_t)b * TD;
            float gir = gb[d]         + score * wscore[d];
            float giz = gb[D + d]     + score * wscore[D + d];
            float gin = gb[2 * D + d] + score * wscore[2 * D + d];
            float rr = sigm(gir + ghr);
            float zz = sigm(giz + ghz);
            float nn = tanhf(gin + rr * ghn);
            float hprev = (t > 0) ? hf[(size_t)b * D + d] : 0.f;
            float hnew = (1.f - zz) * nn + zz * hprev;
            hf[(size_t)b * D + d] = hnew;
            int m = b >> 4, s = d >> 5, lane2 = (b & 15) + (((d >> 3) & 3) << 4), jj = d & 7;
            Aout[(((size_t)m * 32 + s) * 64 + lane2) * 8 + jj] = f2bf(hnew);
            osum += hnew * W_out[d];
        }
        sredO[tid] = osum;
        __syncthreads();
        if (tid < 32) {
            float v = sredO[tid];
            #pragma unroll
            for (int q = 1; q < 8; ++q) v += sredO[tid + q * 32];
            spart[((size_t)t * B + bh * 32 + tid) * 64 + dt] = v;
        }
        grid_sync(bar);
    }

    // ---- Phase D: final output (block 0) ----
    if (n == 0) {
        for (int idx = tid; idx < B * C; idx += 256) {
            int b = idx / C, t = idx % C;
            float s = b_out[0];
            const float* sp = spart + ((size_t)t * B + b) * 64;
            #pragma unroll
            for (int k = 0; k < 64; ++k) s += sp[k];
            out[idx] = sigm(s);
        }
    }
}

extern "C" void kernel_launch(void* const* d_in, const int* in_sizes, int n_in,
                              void* d_out, int out_size, void* d_ws, size_t ws_size,
                              hipStream_t stream) {
    const float* feat  = (const float*)d_in[0];
    const float* a_w   = (const float*)d_in[1];
    const float* W_ih  = (const float*)d_in[2];
    const float* W_hh  = (const float*)d_in[3];
    const float* b_ih  = (const float*)d_in[4];
    const float* b_hh  = (const float*)d_in[5];
    const float* W_out = (const float*)d_in[6];
    const float* b_out = (const float*)d_in[7];
    float* out = (float*)d_out;
    float* ws = (float*)d_ws;

    float* part    = ws;                           // B*16*D      = 1,048,576 f
    float* ml      = part + (size_t)B * 16 * D;    // B*16*2      = 2,048 f
    float* gi0     = ml + B * 16 * 2;              // B*TD        = 196,608 f
    float* hf      = gi0 + (size_t)B * TD;         // B*D         = 65,536 f
    float* spart   = hf + B * D;                   // C*B*64      = 40,960 f
    float* wscore  = spart + (size_t)C * B * 64;   // TD          = 3,072 f
    short* pooledP = (short*)(wscore + TD);        // B*D shorts
    short* hp0     = pooledP + (size_t)B * D;
    short* hp1     = hp0 + (size_t)B * D;
    short* BihP    = hp1 + (size_t)B * D;          // D*TD shorts
    short* BhhP    = BihP + (size_t)D * TD;        // D*TD shorts
    unsigned* bar  = (unsigned*)(BhhP + (size_t)D * TD);  // 8 u32

    k_pre<<<dim3(4108), 256, 0, stream>>>(feat, a_w, W_ih, W_hh, part, ml,
                                          BihP, BhhP, wscore, bar);
    k_fused<<<dim3(NBLK), 256, 0, stream>>>((const s8v*)BihP, (const s8v*)BhhP,
                                            part, ml, pooledP, hp0, hp1, hf, gi0,
                                            wscore, b_ih, b_hh, W_out, b_out,
                                            spart, out, bar);
}

// Round 5
// 573.760 us; speedup vs baseline: 1.1240x; 1.1240x over previous
//
#include <hip/hip_runtime.h>
#include <hip/hip_bf16.h>
#include <math.h>

#define B 64
#define S 1024
#define D 1024
#define C 10
#define TD 3072  // 3*D
#define NBLK 128 // blocks in fused kernel

typedef __attribute__((ext_vector_type(8))) short s8v;   // 8 bf16 (A/B frag)
typedef __attribute__((ext_vector_type(4))) float f4v;   // 4 f32  (C/D frag)

__device__ __forceinline__ float wave_sum_bc(float v) {
    #pragma unroll
    for (int off = 1; off < 64; off <<= 1) v += __shfl_xor(v, off, 64);
    return v;
}
__device__ __forceinline__ float sigm(float x) { return 1.0f / (1.0f + expf(-x)); }
__device__ __forceinline__ short f2bf(float f) {
    __hip_bfloat16 h = __float2bfloat16(f);
    return *reinterpret_cast<short*>(&h);
}

// ---------------------------------------------------------------------------
// Grid barrier. RELAXED spin (sc1 load from L3, no L2-inv per poll);
// one release fence before arrival, one acquire fence after exit.
__device__ __forceinline__ void grid_sync(unsigned* bar) {
    __syncthreads();  // drains vmcnt: all this block's global stores are in L2
    if (threadIdx.x == 0) {
        unsigned g = __hip_atomic_load(&bar[1], __ATOMIC_RELAXED, __HIP_MEMORY_SCOPE_AGENT);
        __threadfence();  // release: write back dirty L2 (hp/spart slices)
        unsigned arrived = __hip_atomic_fetch_add(&bar[0], 1u, __ATOMIC_RELAXED,
                                                  __HIP_MEMORY_SCOPE_AGENT);
        if (arrived == NBLK - 1) {
            __hip_atomic_store(&bar[0], 0u, __ATOMIC_RELAXED, __HIP_MEMORY_SCOPE_AGENT);
            // RELEASE orders the cnt-reset before the gen flip.
            __hip_atomic_store(&bar[1], g + 1u, __ATOMIC_RELEASE, __HIP_MEMORY_SCOPE_AGENT);
        } else {
            while (__hip_atomic_load(&bar[1], __ATOMIC_RELAXED, __HIP_MEMORY_SCOPE_AGENT) == g)
                __builtin_amdgcn_s_sleep(2);
        }
        __threadfence();  // acquire: one L2 inv; LDS/registers are immune
    }
    __syncthreads();
}

// ---------------------------------------------------------------------------
// k_pre: block-role merged prologue (unchanged from R4 — HBM-roofline).
__global__ __launch_bounds__(256) void k_pre(const float* __restrict__ feat,
        const float* __restrict__ a_w, const float* __restrict__ W_ih,
        const float* __restrict__ W_hh, float* __restrict__ part, float* __restrict__ ml,
        short* __restrict__ BihP, short* __restrict__ BhhP, float* __restrict__ wscore,
        unsigned* __restrict__ bar) {
    __shared__ float sacc[4][1024];
    __shared__ float sml[4][2];
    int n = blockIdx.x, tid = threadIdx.x;

    if (n >= 1024) {
        if (n < 4096) {  // pack W
            int rel = n - 1024;
            const float* Wsrc = (rel < 1536) ? W_ih : W_hh;
            short* dst = (rel < 1536) ? BihP : BhhP;
            int stride = (rel < 1536) ? (D + 1) : D;
            int rn = (rel < 1536) ? rel : rel - 1536;
            int gid = rn * 256 + tid;
            int fid = gid >> 6, l = gid & 63;
            int s = fid & 31, g = (fid >> 5) % 3, dt = fid / 96;
            int row = g * 1024 + dt * 16 + (l & 15);
            int k0 = s * 32 + ((l >> 4) << 3);
            const float* src = Wsrc + (size_t)row * stride + k0;
            short v[8];
            #pragma unroll
            for (int j = 0; j < 8; ++j) v[j] = f2bf(src[j]);
            short* d = dst + ((size_t)fid * 64 + l) * 8;
            #pragma unroll
            for (int j = 0; j < 8; ++j) d[j] = v[j];
        } else {  // wscore + barrier init
            int j = (n - 4096) * 256 + tid;
            wscore[j] = W_ih[(size_t)j * (D + 1) + D];
            if (n == 4096 && tid < 8) bar[tid] = 0u;
        }
        return;
    }

    int ch = n & 15, b = n >> 4;
    int w = tid >> 6, lane = tid & 63;
    float4 aw[4], acc[4];
    #pragma unroll
    for (int r = 0; r < 4; ++r) {
        aw[r] = *reinterpret_cast<const float4*>(&a_w[r * 256 + lane * 4]);
        acc[r] = make_float4(0.f, 0.f, 0.f, 0.f);
    }
    float m = -INFINITY, l = 0.f;
    const float* fb = feat + ((size_t)b * S + ch * 64 + w * 16) * D;
    for (int i = 0; i < 16; ++i) {
        float4 f[4];
        #pragma unroll
        for (int r = 0; r < 4; ++r)
            f[r] = *reinterpret_cast<const float4*>(&fb[(size_t)i * D + r * 256 + lane * 4]);
        float dot = 0.f;
        #pragma unroll
        for (int r = 0; r < 4; ++r)
            dot += f[r].x * aw[r].x + f[r].y * aw[r].y + f[r].z * aw[r].z + f[r].w * aw[r].w;
        dot = wave_sum_bc(dot);
        if (dot <= m) {
            float wg = expf(dot - m);
            l += wg;
            #pragma unroll
            for (int r = 0; r < 4; ++r) {
                acc[r].x += wg * f[r].x; acc[r].y += wg * f[r].y;
                acc[r].z += wg * f[r].z; acc[r].w += wg * f[r].w;
            }
        } else {
            float sc = expf(m - dot);
            l = l * sc + 1.f;
            #pragma unroll
            for (int r = 0; r < 4; ++r) {
                acc[r].x = acc[r].x * sc + f[r].x; acc[r].y = acc[r].y * sc + f[r].y;
                acc[r].z = acc[r].z * sc + f[r].z; acc[r].w = acc[r].w * sc + f[r].w;
            }
            m = dot;
        }
    }
    #pragma unroll
    for (int r = 0; r < 4; ++r)
        *reinterpret_cast<float4*>(&sacc[w][r * 256 + lane * 4]) = acc[r];
    if (lane == 0) { sml[w][0] = m; sml[w][1] = l; }
    __syncthreads();
    float m0 = sml[0][0], m1 = sml[1][0], m2 = sml[2][0], m3 = sml[3][0];
    float mg = fmaxf(fmaxf(m0, m1), fmaxf(m2, m3));
    float s0 = expf(m0 - mg), s1 = expf(m1 - mg), s2 = expf(m2 - mg), s3 = expf(m3 - mg);
    int c = tid * 4;
    float4 a0 = *reinterpret_cast<float4*>(&sacc[0][c]);
    float4 a1 = *reinterpret_cast<float4*>(&sacc[1][c]);
    float4 a2 = *reinterpret_cast<float4*>(&sacc[2][c]);
    float4 a3 = *reinterpret_cast<float4*>(&sacc[3][c]);
    float4 o;
    o.x = s0 * a0.x + s1 * a1.x + s2 * a2.x + s3 * a3.x;
    o.y = s0 * a0.y + s1 * a1.y + s2 * a2.y + s3 * a3.y;
    o.z = s0 * a0.z + s1 * a1.z + s2 * a2.z + s3 * a3.z;
    o.w = s0 * a0.w + s1 * a1.w + s2 * a2.w + s3 * a3.w;
    *reinterpret_cast<float4*>(&part[((size_t)b * 16 + ch) * D + c]) = o;
    if (tid == 0) {
        float lg = s0 * sml[0][1] + s1 * sml[1][1] + s2 * sml[2][1] + s3 * sml[3][1];
        ml[(b * 16 + ch) * 2] = mg;
        ml[(b * 16 + ch) * 2 + 1] = lg;
    }
}

// ---------------------------------------------------------------------------
// k_fused: pool-combine+packA -> gi0 GEMM (kept in LDS) -> 10 GRU steps -> final.
// All block-local step data lives in LDS/registers (immune to barrier L2-inv);
// only hp (packed h) and spart cross blocks.
__global__ __launch_bounds__(256, 1) void k_fused(const s8v* __restrict__ BihP,
        const s8v* __restrict__ BhhPv, const float* __restrict__ part,
        const float* __restrict__ ml, short* __restrict__ pooledP,
        short* __restrict__ hp0, short* __restrict__ hp1,
        const float* __restrict__ wscore,
        const float* __restrict__ b_ih, const float* __restrict__ b_hh,
        const float* __restrict__ W_out, const float* __restrict__ b_out,
        float* __restrict__ spart, float* __restrict__ out, unsigned* __restrict__ bar) {
    __shared__ float psum[4][32][49];
    __shared__ float gilds[32][49];   // 48 used: [b-local][gate*16+ld]
    __shared__ float hlds[32][17];    // 16 used: h_prev fp32, block-local
    __shared__ float sredS[32][8];
    __shared__ float sredO[256];
    int tid = threadIdx.x, w = tid >> 6, l = tid & 63;
    int n = blockIdx.x, xcd = n & 7, i = n >> 3;
    int dt = xcd * 8 + (i & 7), bh = i >> 3;

    // ---- Phase A: pool combine + pack A-fragments (blocks 0..63) ----
    if (n < 64) {
        int b = n;
        float mg = -INFINITY;
        #pragma unroll
        for (int q = 0; q < 16; ++q) mg = fmaxf(mg, ml[(b * 16 + q) * 2]);
        float denom = 0.f, sc[16];
        #pragma unroll
        for (int q = 0; q < 16; ++q) {
            sc[q] = expf(ml[(b * 16 + q) * 2] - mg);
            denom += sc[q] * ml[(b * 16 + q) * 2 + 1];
        }
        float inv = 1.f / denom;
        int c = tid * 4;
        float4 o = make_float4(0.f, 0.f, 0.f, 0.f);
        #pragma unroll
        for (int q = 0; q < 16; ++q) {
            float4 p = *reinterpret_cast<const float4*>(&part[((size_t)b * 16 + q) * D + c]);
            o.x += sc[q] * p.x; o.y += sc[q] * p.y; o.z += sc[q] * p.z; o.w += sc[q] * p.w;
        }
        float ov[4] = {o.x * inv, o.y * inv, o.z * inv, o.w * inv};
        int m = b >> 4;
        #pragma unroll
        for (int j4 = 0; j4 < 4; ++j4) {
            int d = c + j4;
            int s = d >> 5, lane2 = (b & 15) + (((d >> 3) & 3) << 4), jj = d & 7;
            pooledP[(((size_t)m * 32 + s) * 64 + lane2) * 8 + jj] = f2bf(ov[j4]);
        }
    }
    grid_sync(bar);

    // ---- Preload per-thread epilogue constants (L2-warm now, regs forever) ----
    int lb = tid & 31;
    int ld0 = tid >> 5;  // 0..7
    float bhh[2][3], wsc[2][3], wout[2];
    #pragma unroll
    for (int pp = 0; pp < 2; ++pp) {
        int d = dt * 16 + ld0 + pp * 8;
        #pragma unroll
        for (int g = 0; g < 3; ++g) {
            bhh[pp][g] = b_hh[g * D + d];
            wsc[pp][g] = wscore[g * D + d];
        }
        wout[pp] = W_out[d];
    }
    float bo = b_out[0];

    // ---- Phase B: gi0 = pooled @ W_ih^T + b_ih, result kept in LDS ----
    {
        const s8v* Ap = reinterpret_cast<const s8v*>(pooledP);
        f4v acc[2][3];
        #pragma unroll
        for (int mi = 0; mi < 2; ++mi)
            #pragma unroll
            for (int g = 0; g < 3; ++g) acc[mi][g] = (f4v){0.f, 0.f, 0.f, 0.f};
        #pragma unroll 2
        for (int s8 = 0; s8 < 8; ++s8) {
            int s = w * 8 + s8;
            s8v a0 = Ap[(size_t)((bh * 2 + 0) * 32 + s) * 64 + l];
            s8v a1 = Ap[(size_t)((bh * 2 + 1) * 32 + s) * 64 + l];
            s8v b0 = BihP[(size_t)((dt * 3 + 0) * 32 + s) * 64 + l];
            s8v b1 = BihP[(size_t)((dt * 3 + 1) * 32 + s) * 64 + l];
            s8v b2 = BihP[(size_t)((dt * 3 + 2) * 32 + s) * 64 + l];
            acc[0][0] = __builtin_amdgcn_mfma_f32_16x16x32_bf16(a0, b0, acc[0][0], 0, 0, 0);
            acc[0][1] = __builtin_amdgcn_mfma_f32_16x16x32_bf16(a0, b1, acc[0][1], 0, 0, 0);
            acc[0][2] = __builtin_amdgcn_mfma_f32_16x16x32_bf16(a0, b2, acc[0][2], 0, 0, 0);
            acc[1][0] = __builtin_amdgcn_mfma_f32_16x16x32_bf16(a1, b0, acc[1][0], 0, 0, 0);
            acc[1][1] = __builtin_amdgcn_mfma_f32_16x16x32_bf16(a1, b1, acc[1][1], 0, 0, 0);
            acc[1][2] = __builtin_amdgcn_mfma_f32_16x16x32_bf16(a1, b2, acc[1][2], 0, 0, 0);
        }
        #pragma unroll
        for (int mi = 0; mi < 2; ++mi)
            #pragma unroll
            for (int g = 0; g < 3; ++g)
                #pragma unroll
                for (int r = 0; r < 4; ++r)
                    psum[w][mi * 16 + (l >> 4) * 4 + r][g * 16 + (l & 15)] = acc[mi][g][r];
        __syncthreads();
        #pragma unroll
        for (int pp = 0; pp < 2; ++pp) {
            int ld = ld0 + pp * 8;
            #pragma unroll
            for (int g = 0; g < 3; ++g) {
                int c48 = g * 16 + ld;
                float v = psum[0][lb][c48] + psum[1][lb][c48] + psum[2][lb][c48] + psum[3][lb][c48];
                gilds[lb][c48] = v + b_ih[g * 1024 + dt * 16 + ld];
            }
        }
    }

    // ---- W_hh B-fragments into registers once ----
    s8v Bw0[8], Bw1[8], Bw2[8];
    #pragma unroll
    for (int s8 = 0; s8 < 8; ++s8) {
        int s = w * 8 + s8;
        Bw0[s8] = BhhPv[(size_t)((dt * 3 + 0) * 32 + s) * 64 + l];
        Bw1[s8] = BhhPv[(size_t)((dt * 3 + 1) * 32 + s) * 64 + l];
        Bw2[s8] = BhhPv[(size_t)((dt * 3 + 2) * 32 + s) * 64 + l];
    }

    // ---- Phase C: 10 GRU steps ----
    for (int t = 0; t < C; ++t) {
        __syncthreads();  // psum WAR; gilds ready (t==0)
        if (t > 0) {
            int grp = tid >> 5;
            const float* sp = spart + ((size_t)(t - 1) * B + bh * 32 + lb) * 64 + grp * 8;
            float sv = 0.f;
            #pragma unroll
            for (int q = 0; q < 8; ++q) sv += sp[q];
            sredS[lb][grp] = sv;
        }
        f4v acc[2][3];
        #pragma unroll
        for (int mi = 0; mi < 2; ++mi)
            #pragma unroll
            for (int g = 0; g < 3; ++g) acc[mi][g] = (f4v){0.f, 0.f, 0.f, 0.f};
        if (t > 0) {
            const s8v* Ain = reinterpret_cast<const s8v*>((t & 1) ? hp1 : hp0);
            #pragma unroll 2
            for (int s8 = 0; s8 < 8; ++s8) {
                int s = w * 8 + s8;
                s8v a0 = Ain[(size_t)((bh * 2 + 0) * 32 + s) * 64 + l];
                s8v a1 = Ain[(size_t)((bh * 2 + 1) * 32 + s) * 64 + l];
                acc[0][0] = __builtin_amdgcn_mfma_f32_16x16x32_bf16(a0, Bw0[s8], acc[0][0], 0, 0, 0);
                acc[0][1] = __builtin_amdgcn_mfma_f32_16x16x32_bf16(a0, Bw1[s8], acc[0][1], 0, 0, 0);
                acc[0][2] = __builtin_amdgcn_mfma_f32_16x16x32_bf16(a0, Bw2[s8], acc[0][2], 0, 0, 0);
                acc[1][0] = __builtin_amdgcn_mfma_f32_16x16x32_bf16(a1, Bw0[s8], acc[1][0], 0, 0, 0);
                acc[1][1] = __builtin_amdgcn_mfma_f32_16x16x32_bf16(a1, Bw1[s8], acc[1][1], 0, 0, 0);
                acc[1][2] = __builtin_amdgcn_mfma_f32_16x16x32_bf16(a1, Bw2[s8], acc[1][2], 0, 0, 0);
            }
        }
        #pragma unroll
        for (int mi = 0; mi < 2; ++mi)
            #pragma unroll
            for (int g = 0; g < 3; ++g)
                #pragma unroll
                for (int r = 0; r < 4; ++r)
                    psum[w][mi * 16 + (l >> 4) * 4 + r][g * 16 + (l & 15)] = acc[mi][g][r];
        __syncthreads();

        int b = bh * 32 + lb;
        float score = 0.f;
        if (t > 0) {
            float ssum = bo;
            #pragma unroll
            for (int g = 0; g < 8; ++g) ssum += sredS[lb][g];
            score = sigm(ssum);
        }
        short* Aout = (t & 1) ? hp0 : hp1;
        float osum = 0.f;
        #pragma unroll
        for (int pp = 0; pp < 2; ++pp) {
            int ld = ld0 + pp * 8;
            int d = dt * 16 + ld;
            float ghr = bhh[pp][0], ghz = bhh[pp][1], ghn = bhh[pp][2];
            if (t > 0) {
                #pragma unroll
                for (int ww = 0; ww < 4; ++ww) {
                    ghr += psum[ww][lb][ld];
                    ghz += psum[ww][lb][16 + ld];
                    ghn += psum[ww][lb][32 + ld];
                }
            }
            float gir = gilds[lb][ld]      + score * wsc[pp][0];
            float giz = gilds[lb][16 + ld] + score * wsc[pp][1];
            float gin = gilds[lb][32 + ld] + score * wsc[pp][2];
            float rr = sigm(gir + ghr);
            float zz = sigm(giz + ghz);
            float nn = tanhf(gin + rr * ghn);
            float hprev = (t > 0) ? hlds[lb][ld] : 0.f;
            float hnew = (1.f - zz) * nn + zz * hprev;
            hlds[lb][ld] = hnew;  // same thread reads it next step
            int m = b >> 4, s = d >> 5, lane2 = (b & 15) + (((d >> 3) & 3) << 4), jj = d & 7;
            Aout[(((size_t)m * 32 + s) * 64 + lane2) * 8 + jj] = f2bf(hnew);
            osum += hnew * wout[pp];
        }
        sredO[tid] = osum;
        __syncthreads();
        if (tid < 32) {
            float v = sredO[tid];
            #pragma unroll
            for (int q = 1; q < 8; ++q) v += sredO[tid + q * 32];
            spart[((size_t)t * B + bh * 32 + tid) * 64 + dt] = v;
        }
        grid_sync(bar);
    }

    // ---- Phase D: final output (block 0) ----
    if (n == 0) {
        for (int idx = tid; idx < B * C; idx += 256) {
            int b = idx / C, t = idx % C;
            float s = bo;
            const float* sp = spart + ((size_t)t * B + b) * 64;
            #pragma unroll
            for (int k = 0; k < 64; ++k) s += sp[k];
            out[idx] = sigm(s);
        }
    }
}

extern "C" void kernel_launch(void* const* d_in, const int* in_sizes, int n_in,
                              void* d_out, int out_size, void* d_ws, size_t ws_size,
                              hipStream_t stream) {
    const float* feat  = (const float*)d_in[0];
    const float* a_w   = (const float*)d_in[1];
    const float* W_ih  = (const float*)d_in[2];
    const float* W_hh  = (const float*)d_in[3];
    const float* b_ih  = (const float*)d_in[4];
    const float* b_hh  = (const float*)d_in[5];
    const float* W_out = (const float*)d_in[6];
    const float* b_out = (const float*)d_in[7];
    float* out = (float*)d_out;
    float* ws = (float*)d_ws;

    float* part    = ws;                           // B*16*D f
    float* ml      = part + (size_t)B * 16 * D;    // B*16*2 f
    float* spart   = ml + B * 16 * 2;              // C*B*64 f
    float* wscore  = spart + (size_t)C * B * 64;   // TD f
    short* pooledP = (short*)(wscore + TD);        // B*D sh
    short* hp0     = pooledP + (size_t)B * D;      // B*D sh
    short* hp1     = hp0 + (size_t)B * D;          // B*D sh
    short* BihP    = hp1 + (size_t)B * D;          // D*TD sh
    short* BhhP    = BihP + (size_t)D * TD;        // D*TD sh
    unsigned* bar  = (unsigned*)(BhhP + (size_t)D * TD);  // 8 u32

    k_pre<<<dim3(4108), 256, 0, stream>>>(feat, a_w, W_ih, W_hh, part, ml,
                                          BihP, BhhP, wscore, bar);
    k_fused<<<dim3(NBLK), 256, 0, stream>>>((const s8v*)BihP, (const s8v*)BhhP,
                                            part, ml, pooledP, hp0, hp1,
                                            wscore, b_ih, b_hh, W_out, b_out,
                                            spart, out, bar);
}

// Round 6
// 121.505 us; speedup vs baseline: 5.3077x; 4.7221x over previous
//
#include <hip/hip_runtime.h>
#include <hip/hip_bf16.h>
#include <math.h>

#define B 64
#define S 1024
#define D 1024
#define C 10
#define TD 3072  // 3*D

typedef __attribute__((ext_vector_type(8))) short s8v;   // 8 bf16 (A/B frag)
typedef __attribute__((ext_vector_type(4))) float f4v;   // 4 f32  (C/D frag)

__device__ __forceinline__ float wave_sum_bc(float v) {
    #pragma unroll
    for (int off = 1; off < 64; off <<= 1) v += __shfl_xor(v, off, 64);
    return v;
}
__device__ __forceinline__ float sigm(float x) { return 1.0f / (1.0f + expf(-x)); }
__device__ __forceinline__ short f2bf(float f) {
    __hip_bfloat16 h = __float2bfloat16(f);
    return *reinterpret_cast<short*>(&h);
}

// ---------------------------------------------------------------------------
// k_pre: block-role merged prologue.
//   [0,1024)      online-softmax pooling partials over feat (HBM-roofline term)
//   [1024,2560)   pack W_ih -> bf16 B-fragments (stride D+1)
//   [2560,4096)   pack W_hh -> bf16 B-fragments (stride D)
//   [4096,4108)   wscore extraction
__global__ __launch_bounds__(256) void k_pre(const float* __restrict__ feat,
        const float* __restrict__ a_w, const float* __restrict__ W_ih,
        const float* __restrict__ W_hh, float* __restrict__ part, float* __restrict__ ml,
        short* __restrict__ BihP, short* __restrict__ BhhP, float* __restrict__ wscore) {
    __shared__ float sacc[4][1024];
    __shared__ float sml[4][2];
    int n = blockIdx.x, tid = threadIdx.x;

    if (n >= 1024) {
        if (n < 4096) {  // pack W
            int rel = n - 1024;
            const float* Wsrc = (rel < 1536) ? W_ih : W_hh;
            short* dst = (rel < 1536) ? BihP : BhhP;
            int stride = (rel < 1536) ? (D + 1) : D;
            int rn = (rel < 1536) ? rel : rel - 1536;
            int gid = rn * 256 + tid;
            int fid = gid >> 6, l = gid & 63;
            int s = fid & 31, g = (fid >> 5) % 3, dt = fid / 96;
            int row = g * 1024 + dt * 16 + (l & 15);
            int k0 = s * 32 + ((l >> 4) << 3);
            const float* src = Wsrc + (size_t)row * stride + k0;
            short v[8];
            #pragma unroll
            for (int j = 0; j < 8; ++j) v[j] = f2bf(src[j]);
            short* d = dst + ((size_t)fid * 64 + l) * 8;
            #pragma unroll
            for (int j = 0; j < 8; ++j) d[j] = v[j];
        } else {  // wscore
            int j = (n - 4096) * 256 + tid;
            wscore[j] = W_ih[(size_t)j * (D + 1) + D];
        }
        return;
    }

    int ch = n & 15, b = n >> 4;
    int w = tid >> 6, lane = tid & 63;
    float4 aw[4], acc[4];
    #pragma unroll
    for (int r = 0; r < 4; ++r) {
        aw[r] = *reinterpret_cast<const float4*>(&a_w[r * 256 + lane * 4]);
        acc[r] = make_float4(0.f, 0.f, 0.f, 0.f);
    }
    float m = -INFINITY, l = 0.f;
    const float* fb = feat + ((size_t)b * S + ch * 64 + w * 16) * D;
    for (int i = 0; i < 16; ++i) {
        float4 f[4];
        #pragma unroll
        for (int r = 0; r < 4; ++r)
            f[r] = *reinterpret_cast<const float4*>(&fb[(size_t)i * D + r * 256 + lane * 4]);
        float dot = 0.f;
        #pragma unroll
        for (int r = 0; r < 4; ++r)
            dot += f[r].x * aw[r].x + f[r].y * aw[r].y + f[r].z * aw[r].z + f[r].w * aw[r].w;
        dot = wave_sum_bc(dot);
        if (dot <= m) {
            float wg = expf(dot - m);
            l += wg;
            #pragma unroll
            for (int r = 0; r < 4; ++r) {
                acc[r].x += wg * f[r].x; acc[r].y += wg * f[r].y;
                acc[r].z += wg * f[r].z; acc[r].w += wg * f[r].w;
            }
        } else {
            float sc = expf(m - dot);
            l = l * sc + 1.f;
            #pragma unroll
            for (int r = 0; r < 4; ++r) {
                acc[r].x = acc[r].x * sc + f[r].x; acc[r].y = acc[r].y * sc + f[r].y;
                acc[r].z = acc[r].z * sc + f[r].z; acc[r].w = acc[r].w * sc + f[r].w;
            }
            m = dot;
        }
    }
    #pragma unroll
    for (int r = 0; r < 4; ++r)
        *reinterpret_cast<float4*>(&sacc[w][r * 256 + lane * 4]) = acc[r];
    if (lane == 0) { sml[w][0] = m; sml[w][1] = l; }
    __syncthreads();
    float m0 = sml[0][0], m1 = sml[1][0], m2 = sml[2][0], m3 = sml[3][0];
    float mg = fmaxf(fmaxf(m0, m1), fmaxf(m2, m3));
    float s0 = expf(m0 - mg), s1 = expf(m1 - mg), s2 = expf(m2 - mg), s3 = expf(m3 - mg);
    int c = tid * 4;
    float4 a0 = *reinterpret_cast<float4*>(&sacc[0][c]);
    float4 a1 = *reinterpret_cast<float4*>(&sacc[1][c]);
    float4 a2 = *reinterpret_cast<float4*>(&sacc[2][c]);
    float4 a3 = *reinterpret_cast<float4*>(&sacc[3][c]);
    float4 o;
    o.x = s0 * a0.x + s1 * a1.x + s2 * a2.x + s3 * a3.x;
    o.y = s0 * a0.y + s1 * a1.y + s2 * a2.y + s3 * a3.y;
    o.z = s0 * a0.z + s1 * a1.z + s2 * a2.z + s3 * a3.z;
    o.w = s0 * a0.w + s1 * a1.w + s2 * a2.w + s3 * a3.w;
    *reinterpret_cast<float4*>(&part[((size_t)b * 16 + ch) * D + c]) = o;
    if (tid == 0) {
        float lg = s0 * sml[0][1] + s1 * sml[1][1] + s2 * sml[2][1] + s3 * sml[3][1];
        ml[(b * 16 + ch) * 2] = mg;
        ml[(b * 16 + ch) * 2 + 1] = lg;
    }
}

// ---------------------------------------------------------------------------
// k_mid: pool-combine + pack A-fragments. 64 blocks (one per batch).
__global__ __launch_bounds__(256) void k_mid(const float* __restrict__ part,
        const float* __restrict__ ml, short* __restrict__ pooledP) {
    int b = blockIdx.x, tid = threadIdx.x;
    float mg = -INFINITY;
    #pragma unroll
    for (int q = 0; q < 16; ++q) mg = fmaxf(mg, ml[(b * 16 + q) * 2]);
    float denom = 0.f, sc[16];
    #pragma unroll
    for (int q = 0; q < 16; ++q) {
        sc[q] = expf(ml[(b * 16 + q) * 2] - mg);
        denom += sc[q] * ml[(b * 16 + q) * 2 + 1];
    }
    float inv = 1.f / denom;
    int c = tid * 4;
    float4 o = make_float4(0.f, 0.f, 0.f, 0.f);
    #pragma unroll
    for (int q = 0; q < 16; ++q) {
        float4 p = *reinterpret_cast<const float4*>(&part[((size_t)b * 16 + q) * D + c]);
        o.x += sc[q] * p.x; o.y += sc[q] * p.y; o.z += sc[q] * p.z; o.w += sc[q] * p.w;
    }
    float ov[4] = {o.x * inv, o.y * inv, o.z * inv, o.w * inv};
    int m = b >> 4;
    #pragma unroll
    for (int j4 = 0; j4 < 4; ++j4) {
        int d = c + j4;
        int s = d >> 5, lane2 = (b & 15) + (((d >> 3) & 3) << 4), jj = d & 7;
        pooledP[(((size_t)m * 32 + s) * 64 + lane2) * 8 + jj] = f2bf(ov[j4]);
    }
}

// ---------------------------------------------------------------------------
// k_step: one GRU step (t==0: A=pooledP,B=W_ih -> gi0 + step-0 epilogue;
//         t>0: A=hp,B=W_hh -> gh + epilogue).
// Grid 256 = (dt 0..63) x (bh 0..3), XCD-pinned; block 256 = 4 waves (k-quarters).
// Block output: 16 batches x 16 d x 3 gates.
__global__ __launch_bounds__(256) void k_step(const s8v* __restrict__ Bp,
        const s8v* __restrict__ Ain, short* __restrict__ Aout, float* __restrict__ hf,
        float* __restrict__ gi0, const float* __restrict__ wscore,
        const float* __restrict__ b_ih, const float* __restrict__ b_hh,
        const float* __restrict__ W_out, const float* __restrict__ b_out,
        float* __restrict__ spart, int t) {
    __shared__ float psum[4][16][49];
    __shared__ float sredS[16][17];
    __shared__ float sredO[16][17];
    int tid = threadIdx.x, w = tid >> 6, l = tid & 63;
    int n = blockIdx.x, xcd = n & 7, slot = n >> 3;
    int dt = xcd * 8 + (slot & 7), bh = slot >> 3;
    int bq0 = bh * 16;
    int lb = tid & 15, c = tid >> 4;

    if (t > 0) {  // pre-reduce previous step's score partials (64 -> 16 per batch)
        const float* sp = spart + (((size_t)(t - 1) * B + bq0 + lb)) * 64 + c * 4;
        sredS[lb][c] = sp[0] + sp[1] + sp[2] + sp[3];
    }

    f4v acc[3];
    #pragma unroll
    for (int g = 0; g < 3; ++g) acc[g] = (f4v){0.f, 0.f, 0.f, 0.f};
    #pragma unroll 2
    for (int s8 = 0; s8 < 8; ++s8) {
        int s = w * 8 + s8;
        s8v a  = Ain[((size_t)bh * 32 + s) * 64 + l];
        s8v b0 = Bp[((size_t)(dt * 3 + 0) * 32 + s) * 64 + l];
        s8v b1 = Bp[((size_t)(dt * 3 + 1) * 32 + s) * 64 + l];
        s8v b2 = Bp[((size_t)(dt * 3 + 2) * 32 + s) * 64 + l];
        acc[0] = __builtin_amdgcn_mfma_f32_16x16x32_bf16(a, b0, acc[0], 0, 0, 0);
        acc[1] = __builtin_amdgcn_mfma_f32_16x16x32_bf16(a, b1, acc[1], 0, 0, 0);
        acc[2] = __builtin_amdgcn_mfma_f32_16x16x32_bf16(a, b2, acc[2], 0, 0, 0);
    }
    #pragma unroll
    for (int g = 0; g < 3; ++g)
        #pragma unroll
        for (int r = 0; r < 4; ++r)
            psum[w][(l >> 4) * 4 + r][g * 16 + (l & 15)] = acc[g][r];
    __syncthreads();

    int b = bq0 + lb, d = dt * 16 + c;
    float g3[3];
    #pragma unroll
    for (int g = 0; g < 3; ++g) {
        int c48 = g * 16 + c;
        g3[g] = psum[0][lb][c48] + psum[1][lb][c48] + psum[2][lb][c48] + psum[3][lb][c48];
    }
    float gir, giz, gin, ghr, ghz, ghn, hprev;
    if (t == 0) {
        gir = g3[0] + b_ih[d];
        giz = g3[1] + b_ih[D + d];
        gin = g3[2] + b_ih[2 * D + d];
        gi0[(size_t)b * TD + d] = gir;
        gi0[(size_t)b * TD + D + d] = giz;
        gi0[(size_t)b * TD + 2 * D + d] = gin;
        ghr = b_hh[d]; ghz = b_hh[D + d]; ghn = b_hh[2 * D + d];
        hprev = 0.f;
    } else {
        float ssum = b_out[0];
        #pragma unroll
        for (int q = 0; q < 16; ++q) ssum += sredS[lb][q];
        float score = sigm(ssum);
        gir = gi0[(size_t)b * TD + d]         + score * wscore[d];
        giz = gi0[(size_t)b * TD + D + d]     + score * wscore[D + d];
        gin = gi0[(size_t)b * TD + 2 * D + d] + score * wscore[2 * D + d];
        ghr = b_hh[d] + g3[0];
        ghz = b_hh[D + d] + g3[1];
        ghn = b_hh[2 * D + d] + g3[2];
        hprev = hf[(size_t)b * D + d];
    }
    float rr = sigm(gir + ghr);
    float zz = sigm(giz + ghz);
    float nn = tanhf(gin + rr * ghn);
    float hnew = (1.f - zz) * nn + zz * hprev;
    hf[(size_t)b * D + d] = hnew;
    // scatter into next step's A-fragment layout (m = b>>4 == bh)
    int s = d >> 5, lane2 = (b & 15) + (((d >> 3) & 3) << 4), jj = d & 7;
    Aout[(((size_t)bh * 32 + s) * 64 + lane2) * 8 + jj] = f2bf(hnew);

    sredO[lb][c] = hnew * W_out[d];
    __syncthreads();
    if (tid < 16) {
        float v = 0.f;
        #pragma unroll
        for (int q = 0; q < 16; ++q) v += sredO[tid][q];
        spart[((size_t)t * B + bq0 + tid) * 64 + dt] = v;
    }
}

__global__ void k_final(const float* __restrict__ spart, const float* __restrict__ b_out,
                        float* __restrict__ out) {
    int i = blockIdx.x * 256 + threadIdx.x;
    if (i >= B * C) return;
    int b = i / C, t = i % C;
    float s = b_out[0];
    const float* sp = spart + ((size_t)t * B + b) * 64;
    #pragma unroll
    for (int k = 0; k < 64; ++k) s += sp[k];
    out[i] = sigm(s);
}

extern "C" void kernel_launch(void* const* d_in, const int* in_sizes, int n_in,
                              void* d_out, int out_size, void* d_ws, size_t ws_size,
                              hipStream_t stream) {
    const float* feat  = (const float*)d_in[0];
    const float* a_w   = (const float*)d_in[1];
    const float* W_ih  = (const float*)d_in[2];
    const float* W_hh  = (const float*)d_in[3];
    const float* b_ih  = (const float*)d_in[4];
    const float* b_hh  = (const float*)d_in[5];
    const float* W_out = (const float*)d_in[6];
    const float* b_out = (const float*)d_in[7];
    float* out = (float*)d_out;
    float* ws = (float*)d_ws;

    float* part    = ws;                           // B*16*D f
    float* ml      = part + (size_t)B * 16 * D;    // B*16*2 f
    float* gi0     = ml + B * 16 * 2;              // B*TD f
    float* hf      = gi0 + (size_t)B * TD;         // B*D f
    float* spart   = hf + B * D;                   // C*B*64 f
    float* wscore  = spart + (size_t)C * B * 64;   // TD f
    short* pooledP = (short*)(wscore + TD);        // B*D sh
    short* hpA     = pooledP + (size_t)B * D;      // B*D sh
    short* hpB     = hpA + (size_t)B * D;          // B*D sh
    short* BihP    = hpB + (size_t)B * D;          // D*TD sh
    short* BhhP    = BihP + (size_t)D * TD;        // D*TD sh

    k_pre<<<dim3(4108), 256, 0, stream>>>(feat, a_w, W_ih, W_hh, part, ml,
                                          BihP, BhhP, wscore);
    k_mid<<<dim3(64), 256, 0, stream>>>(part, ml, pooledP);
    // t=0: A = pooled, B = W_ih -> writes gi0, hf, hpA, spart[0]
    k_step<<<dim3(256), 256, 0, stream>>>((const s8v*)BihP, (const s8v*)pooledP, hpA,
                                          hf, gi0, wscore, b_ih, b_hh, W_out, b_out,
                                          spart, 0);
    for (int t = 1; t < C; ++t) {
        short* ain = (t & 1) ? hpA : hpB;
        short* aout = (t & 1) ? hpB : hpA;
        k_step<<<dim3(256), 256, 0, stream>>>((const s8v*)BhhP, (const s8v*)ain, aout,
                                              hf, gi0, wscore, b_ih, b_hh, W_out, b_out,
                                              spart, t);
    }
    k_final<<<dim3(3), 256, 0, stream>>>(spart, b_out, out);
}

// Round 7
// 116.629 us; speedup vs baseline: 5.5296x; 1.0418x over previous
//
#include <hip/hip_runtime.h>
#include <hip/hip_bf16.h>
#include <math.h>

#define B 64
#define S 1024
#define D 1024
#define C 10
#define TD 3072  // 3*D

typedef __attribute__((ext_vector_type(8))) short s8v;   // 8 bf16 (A/B frag)
typedef __attribute__((ext_vector_type(4))) float f4v;   // 4 f32  (C/D frag)

__device__ __forceinline__ float wave_sum_bc(float v) {
    #pragma unroll
    for (int off = 1; off < 64; off <<= 1) v += __shfl_xor(v, off, 64);
    return v;
}
__device__ __forceinline__ float sigm(float x) { return 1.0f / (1.0f + expf(-x)); }
__device__ __forceinline__ short f2bf(float f) {
    __hip_bfloat16 h = __float2bfloat16(f);
    return *reinterpret_cast<short*>(&h);
}

// ---------------------------------------------------------------------------
// k_pre: block-role merged prologue (unchanged from R6 — HBM-roofline).
//   [0,1024)      online-softmax pooling partials over feat
//   [1024,2560)   pack W_ih -> bf16 B-fragments (stride D+1)
//   [2560,4096)   pack W_hh -> bf16 B-fragments (stride D)
//   [4096,4108)   wscore extraction
__global__ __launch_bounds__(256) void k_pre(const float* __restrict__ feat,
        const float* __restrict__ a_w, const float* __restrict__ W_ih,
        const float* __restrict__ W_hh, float* __restrict__ part, float* __restrict__ ml,
        short* __restrict__ BihP, short* __restrict__ BhhP, float* __restrict__ wscore) {
    __shared__ float sacc[4][1024];
    __shared__ float sml[4][2];
    int n = blockIdx.x, tid = threadIdx.x;

    if (n >= 1024) {
        if (n < 4096) {  // pack W
            int rel = n - 1024;
            const float* Wsrc = (rel < 1536) ? W_ih : W_hh;
            short* dst = (rel < 1536) ? BihP : BhhP;
            int stride = (rel < 1536) ? (D + 1) : D;
            int rn = (rel < 1536) ? rel : rel - 1536;
            int gid = rn * 256 + tid;
            int fid = gid >> 6, l = gid & 63;
            int s = fid & 31, g = (fid >> 5) % 3, dt = fid / 96;
            int row = g * 1024 + dt * 16 + (l & 15);
            int k0 = s * 32 + ((l >> 4) << 3);
            const float* src = Wsrc + (size_t)row * stride + k0;
            short v[8];
            #pragma unroll
            for (int j = 0; j < 8; ++j) v[j] = f2bf(src[j]);
            short* d = dst + ((size_t)fid * 64 + l) * 8;
            #pragma unroll
            for (int j = 0; j < 8; ++j) d[j] = v[j];
        } else {  // wscore
            int j = (n - 4096) * 256 + tid;
            wscore[j] = W_ih[(size_t)j * (D + 1) + D];
        }
        return;
    }

    int ch = n & 15, b = n >> 4;
    int w = tid >> 6, lane = tid & 63;
    float4 aw[4], acc[4];
    #pragma unroll
    for (int r = 0; r < 4; ++r) {
        aw[r] = *reinterpret_cast<const float4*>(&a_w[r * 256 + lane * 4]);
        acc[r] = make_float4(0.f, 0.f, 0.f, 0.f);
    }
    float m = -INFINITY, l = 0.f;
    const float* fb = feat + ((size_t)b * S + ch * 64 + w * 16) * D;
    for (int i = 0; i < 16; ++i) {
        float4 f[4];
        #pragma unroll
        for (int r = 0; r < 4; ++r)
            f[r] = *reinterpret_cast<const float4*>(&fb[(size_t)i * D + r * 256 + lane * 4]);
        float dot = 0.f;
        #pragma unroll
        for (int r = 0; r < 4; ++r)
            dot += f[r].x * aw[r].x + f[r].y * aw[r].y + f[r].z * aw[r].z + f[r].w * aw[r].w;
        dot = wave_sum_bc(dot);
        if (dot <= m) {
            float wg = expf(dot - m);
            l += wg;
            #pragma unroll
            for (int r = 0; r < 4; ++r) {
                acc[r].x += wg * f[r].x; acc[r].y += wg * f[r].y;
                acc[r].z += wg * f[r].z; acc[r].w += wg * f[r].w;
            }
        } else {
            float sc = expf(m - dot);
            l = l * sc + 1.f;
            #pragma unroll
            for (int r = 0; r < 4; ++r) {
                acc[r].x = acc[r].x * sc + f[r].x; acc[r].y = acc[r].y * sc + f[r].y;
                acc[r].z = acc[r].z * sc + f[r].z; acc[r].w = acc[r].w * sc + f[r].w;
            }
            m = dot;
        }
    }
    #pragma unroll
    for (int r = 0; r < 4; ++r)
        *reinterpret_cast<float4*>(&sacc[w][r * 256 + lane * 4]) = acc[r];
    if (lane == 0) { sml[w][0] = m; sml[w][1] = l; }
    __syncthreads();
    float m0 = sml[0][0], m1 = sml[1][0], m2 = sml[2][0], m3 = sml[3][0];
    float mg = fmaxf(fmaxf(m0, m1), fmaxf(m2, m3));
    float s0 = expf(m0 - mg), s1 = expf(m1 - mg), s2 = expf(m2 - mg), s3 = expf(m3 - mg);
    int c = tid * 4;
    float4 a0 = *reinterpret_cast<float4*>(&sacc[0][c]);
    float4 a1 = *reinterpret_cast<float4*>(&sacc[1][c]);
    float4 a2 = *reinterpret_cast<float4*>(&sacc[2][c]);
    float4 a3 = *reinterpret_cast<float4*>(&sacc[3][c]);
    float4 o;
    o.x = s0 * a0.x + s1 * a1.x + s2 * a2.x + s3 * a3.x;
    o.y = s0 * a0.y + s1 * a1.y + s2 * a2.y + s3 * a3.y;
    o.z = s0 * a0.z + s1 * a1.z + s2 * a2.z + s3 * a3.z;
    o.w = s0 * a0.w + s1 * a1.w + s2 * a2.w + s3 * a3.w;
    *reinterpret_cast<float4*>(&part[((size_t)b * 16 + ch) * D + c]) = o;
    if (tid == 0) {
        float lg = s0 * sml[0][1] + s1 * sml[1][1] + s2 * sml[2][1] + s3 * sml[3][1];
        ml[(b * 16 + ch) * 2] = mg;
        ml[(b * 16 + ch) * 2 + 1] = lg;
    }
}

// ---------------------------------------------------------------------------
// k_mid: pool-combine + pack A-fragments. 64 blocks (one per batch).
__global__ __launch_bounds__(256) void k_mid(const float* __restrict__ part,
        const float* __restrict__ ml, short* __restrict__ pooledP) {
    int b = blockIdx.x, tid = threadIdx.x;
    float mg = -INFINITY;
    #pragma unroll
    for (int q = 0; q < 16; ++q) mg = fmaxf(mg, ml[(b * 16 + q) * 2]);
    float denom = 0.f, sc[16];
    #pragma unroll
    for (int q = 0; q < 16; ++q) {
        sc[q] = expf(ml[(b * 16 + q) * 2] - mg);
        denom += sc[q] * ml[(b * 16 + q) * 2 + 1];
    }
    float inv = 1.f / denom;
    int c = tid * 4;
    float4 o = make_float4(0.f, 0.f, 0.f, 0.f);
    #pragma unroll
    for (int q = 0; q < 16; ++q) {
        float4 p = *reinterpret_cast<const float4*>(&part[((size_t)b * 16 + q) * D + c]);
        o.x += sc[q] * p.x; o.y += sc[q] * p.y; o.z += sc[q] * p.z; o.w += sc[q] * p.w;
    }
    float ov[4] = {o.x * inv, o.y * inv, o.z * inv, o.w * inv};
    int m = b >> 4;
    #pragma unroll
    for (int j4 = 0; j4 < 4; ++j4) {
        int d = c + j4;
        int s = d >> 5, lane2 = (b & 15) + (((d >> 3) & 3) << 4), jj = d & 7;
        pooledP[(((size_t)m * 32 + s) * 64 + lane2) * 8 + jj] = f2bf(ov[j4]);
    }
}

// ---------------------------------------------------------------------------
// k_step: one GRU step. Grid 256 = (dt 0..63)x(bh 0..3) XCD-pinned;
// block 512 = 8 waves (k-eighths, fully unrolled). Early-issued epilogue loads.
// t==0: A=pooledP,B=W_ih -> writes gi0 + step-0 epilogue.
// t>0:  A=hp,B=W_hh; also writes out[:,t-1] (score computed from spart[t-1]).
__global__ __launch_bounds__(512) void k_step(const s8v* __restrict__ Bp,
        const s8v* __restrict__ Ain, short* __restrict__ Aout, float* __restrict__ hf,
        float* __restrict__ gi0, const float* __restrict__ wscore,
        const float* __restrict__ b_ih, const float* __restrict__ b_hh,
        const float* __restrict__ W_out, const float* __restrict__ b_out,
        float* __restrict__ spart, float* __restrict__ out, int t) {
    __shared__ float psum[8][16][49];
    __shared__ float sredS[16][17];
    __shared__ float sredO[16][17];
    int tid = threadIdx.x, w = tid >> 6, l = tid & 63;
    int n = blockIdx.x, xcd = n & 7, slot = n >> 3;
    int dt = xcd * 8 + (slot & 7), bh = slot >> 3;
    int bq0 = bh * 16;
    int lb = tid & 15, c = (tid >> 4) & 15;
    bool epi = (tid < 256);
    int b = bq0 + lb, d = dt * 16 + c;

    // ---- early: issue all epilogue scalar loads (hide under MFMA phase) ----
    float e_bo = 0.f, e_b0 = 0.f, e_b1 = 0.f, e_b2 = 0.f, e_wo = 0.f;
    float e_i0 = 0.f, e_i1 = 0.f, e_i2 = 0.f;
    float e_w0 = 0.f, e_w1 = 0.f, e_w2 = 0.f, e_hf = 0.f;
    if (epi) {
        e_bo = b_out[0];
        e_b0 = b_hh[d]; e_b1 = b_hh[D + d]; e_b2 = b_hh[2 * D + d];
        e_wo = W_out[d];
        if (t == 0) {
            e_i0 = b_ih[d]; e_i1 = b_ih[D + d]; e_i2 = b_ih[2 * D + d];
        } else {
            e_i0 = gi0[(size_t)b * TD + d];
            e_i1 = gi0[(size_t)b * TD + D + d];
            e_i2 = gi0[(size_t)b * TD + 2 * D + d];
            e_w0 = wscore[d]; e_w1 = wscore[D + d]; e_w2 = wscore[2 * D + d];
            e_hf = hf[(size_t)b * D + d];
            const float* sp = spart + ((size_t)(t - 1) * B + b) * 64 + c * 4;
            sredS[lb][c] = sp[0] + sp[1] + sp[2] + sp[3];
        }
    }

    // ---- MFMA phase: k-eighth per wave, fully unrolled ----
    f4v acc[3];
    #pragma unroll
    for (int g = 0; g < 3; ++g) acc[g] = (f4v){0.f, 0.f, 0.f, 0.f};
    #pragma unroll
    for (int s8 = 0; s8 < 4; ++s8) {
        int s = w * 4 + s8;
        s8v a  = Ain[((size_t)bh * 32 + s) * 64 + l];
        s8v b0 = Bp[((size_t)(dt * 3 + 0) * 32 + s) * 64 + l];
        s8v b1 = Bp[((size_t)(dt * 3 + 1) * 32 + s) * 64 + l];
        s8v b2 = Bp[((size_t)(dt * 3 + 2) * 32 + s) * 64 + l];
        acc[0] = __builtin_amdgcn_mfma_f32_16x16x32_bf16(a, b0, acc[0], 0, 0, 0);
        acc[1] = __builtin_amdgcn_mfma_f32_16x16x32_bf16(a, b1, acc[1], 0, 0, 0);
        acc[2] = __builtin_amdgcn_mfma_f32_16x16x32_bf16(a, b2, acc[2], 0, 0, 0);
    }
    #pragma unroll
    for (int g = 0; g < 3; ++g)
        #pragma unroll
        for (int r = 0; r < 4; ++r)
            psum[w][(l >> 4) * 4 + r][g * 16 + (l & 15)] = acc[g][r];
    __syncthreads();

    // ---- epilogue (threads 0..255: one (batch, d) pair each) ----
    if (epi) {
        float g3[3];
        #pragma unroll
        for (int g = 0; g < 3; ++g) {
            int c48 = g * 16 + c;
            float v = 0.f;
            #pragma unroll
            for (int ww = 0; ww < 8; ++ww) v += psum[ww][lb][c48];
            g3[g] = v;
        }
        float gir, giz, gin, ghr, ghz, ghn, hprev;
        if (t == 0) {
            gir = g3[0] + e_i0;
            giz = g3[1] + e_i1;
            gin = g3[2] + e_i2;
            gi0[(size_t)b * TD + d] = gir;
            gi0[(size_t)b * TD + D + d] = giz;
            gi0[(size_t)b * TD + 2 * D + d] = gin;
            ghr = e_b0; ghz = e_b1; ghn = e_b2;
            hprev = 0.f;
        } else {
            float ssum = e_bo;
            #pragma unroll
            for (int q = 0; q < 16; ++q) ssum += sredS[lb][q];
            float score = sigm(ssum);
            if (dt == 0 && c == 0) out[b * C + (t - 1)] = score;  // score IS out[:,t-1]
            gir = e_i0 + score * e_w0;
            giz = e_i1 + score * e_w1;
            gin = e_i2 + score * e_w2;
            ghr = e_b0 + g3[0];
            ghz = e_b1 + g3[1];
            ghn = e_b2 + g3[2];
            hprev = e_hf;
        }
        float rr = sigm(gir + ghr);
        float zz = sigm(giz + ghz);
        float nn = tanhf(gin + rr * ghn);
        float hnew = (1.f - zz) * nn + zz * hprev;
        hf[(size_t)b * D + d] = hnew;
        // scatter into next step's A-fragment layout (m = b>>4 == bh)
        int s = d >> 5, lane2 = (b & 15) + (((d >> 3) & 3) << 4), jj = d & 7;
        Aout[(((size_t)bh * 32 + s) * 64 + lane2) * 8 + jj] = f2bf(hnew);
        sredO[lb][c] = hnew * e_wo;
    }
    __syncthreads();
    if (tid < 16) {
        float v = 0.f;
        #pragma unroll
        for (int q = 0; q < 16; ++q) v += sredO[tid][q];
        spart[((size_t)t * B + bq0 + tid) * 64 + dt] = v;
    }
}

// k_final: only out[:, C-1] remains (steps wrote out[:, 0..C-2]).
__global__ void k_final(const float* __restrict__ spart, const float* __restrict__ b_out,
                        float* __restrict__ out) {
    int b = threadIdx.x;  // 64 threads, 1 block
    float s = b_out[0];
    const float* sp = spart + ((size_t)(C - 1) * B + b) * 64;
    #pragma unroll
    for (int k = 0; k < 64; ++k) s += sp[k];
    out[b * C + (C - 1)] = sigm(s);
}

extern "C" void kernel_launch(void* const* d_in, const int* in_sizes, int n_in,
                              void* d_out, int out_size, void* d_ws, size_t ws_size,
                              hipStream_t stream) {
    const float* feat  = (const float*)d_in[0];
    const float* a_w   = (const float*)d_in[1];
    const float* W_ih  = (const float*)d_in[2];
    const float* W_hh  = (const float*)d_in[3];
    const float* b_ih  = (const float*)d_in[4];
    const float* b_hh  = (const float*)d_in[5];
    const float* W_out = (const float*)d_in[6];
    const float* b_out = (const float*)d_in[7];
    float* out = (float*)d_out;
    float* ws = (float*)d_ws;

    float* part    = ws;                           // B*16*D f
    float* ml      = part + (size_t)B * 16 * D;    // B*16*2 f
    float* gi0     = ml + B * 16 * 2;              // B*TD f
    float* hf      = gi0 + (size_t)B * TD;         // B*D f
    float* spart   = hf + B * D;                   // C*B*64 f
    float* wscore  = spart + (size_t)C * B * 64;   // TD f
    short* pooledP = (short*)(wscore + TD);        // B*D sh
    short* hpA     = pooledP + (size_t)B * D;      // B*D sh
    short* hpB     = hpA + (size_t)B * D;          // B*D sh
    short* BihP    = hpB + (size_t)B * D;          // D*TD sh
    short* BhhP    = BihP + (size_t)D * TD;        // D*TD sh

    k_pre<<<dim3(4108), 256, 0, stream>>>(feat, a_w, W_ih, W_hh, part, ml,
                                          BihP, BhhP, wscore);
    k_mid<<<dim3(64), 256, 0, stream>>>(part, ml, pooledP);
    // t=0: A = pooled, B = W_ih -> writes gi0, hf, hpA, spart[0]
    k_step<<<dim3(256), 512, 0, stream>>>((const s8v*)BihP, (const s8v*)pooledP, hpA,
                                          hf, gi0, wscore, b_ih, b_hh, W_out, b_out,
                                          spart, out, 0);
    for (int t = 1; t < C; ++t) {
        short* ain = (t & 1) ? hpA : hpB;
        short* aout = (t & 1) ? hpB : hpA;
        k_step<<<dim3(256), 512, 0, stream>>>((const s8v*)BhhP, (const s8v*)ain, aout,
                                              hf, gi0, wscore, b_ih, b_hh, W_out, b_out,
                                              spart, out, t);
    }
    k_final<<<dim3(1), 64, 0, stream>>>(spart, b_out, out);
}

// Round 8
// 111.916 us; speedup vs baseline: 5.7624x; 1.0421x over previous
//
#include <hip/hip_runtime.h>
#include <hip/hip_bf16.h>
#include <math.h>

#define B 64
#define S 1024
#define D 1024
#define C 10
#define TD 3072  // 3*D

typedef __attribute__((ext_vector_type(8))) short s8v;   // 8 bf16 (A/B frag)
typedef __attribute__((ext_vector_type(4))) float f4v;   // 4 f32  (C/D frag)
typedef unsigned long long u64;

__device__ __forceinline__ float wave_sum_bc(float v) {
    #pragma unroll
    for (int off = 1; off < 64; off <<= 1) v += __shfl_xor(v, off, 64);
    return v;
}
__device__ __forceinline__ float sigm(float x) { return 1.0f / (1.0f + expf(-x)); }
__device__ __forceinline__ short f2bf(float f) {
    __hip_bfloat16 h = __float2bfloat16(f);
    return *reinterpret_cast<short*>(&h);
}
// Agent-scope relaxed atomics: sc-routed through L3, immune to stale per-XCD L2.
__device__ __forceinline__ u64 aload64(u64* p) {
    return __hip_atomic_load(p, __ATOMIC_RELAXED, __HIP_MEMORY_SCOPE_AGENT);
}
__device__ __forceinline__ void astore64(u64* p, u64 v) {
    __hip_atomic_store(p, v, __ATOMIC_RELAXED, __HIP_MEMORY_SCOPE_AGENT);
}
__device__ __forceinline__ float aloadf(float* p) {
    return __hip_atomic_load(p, __ATOMIC_RELAXED, __HIP_MEMORY_SCOPE_AGENT);
}
__device__ __forceinline__ void astoref(float* p, float v) {
    __hip_atomic_store(p, v, __ATOMIC_RELAXED, __HIP_MEMORY_SCOPE_AGENT);
}

// ---------------------------------------------------------------------------
// k_pre: merged prologue (pooling partials + W packs + wscore + bar zero).
__global__ __launch_bounds__(256) void k_pre(const float* __restrict__ feat,
        const float* __restrict__ a_w, const float* __restrict__ W_ih,
        const float* __restrict__ W_hh, float* __restrict__ part, float* __restrict__ ml,
        short* __restrict__ BihP, short* __restrict__ BhhP, float* __restrict__ wscore,
        unsigned* __restrict__ bar) {
    __shared__ float sacc[4][1024];
    __shared__ float sml[4][2];
    int n = blockIdx.x, tid = threadIdx.x;

    if (n >= 1024) {
        if (n < 4096) {  // pack W
            int rel = n - 1024;
            const float* Wsrc = (rel < 1536) ? W_ih : W_hh;
            short* dst = (rel < 1536) ? BihP : BhhP;
            int stride = (rel < 1536) ? (D + 1) : D;
            int rn = (rel < 1536) ? rel : rel - 1536;
            int gid = rn * 256 + tid;
            int fid = gid >> 6, l = gid & 63;
            int s = fid & 31, g = (fid >> 5) % 3, dt = fid / 96;
            int row = g * 1024 + dt * 16 + (l & 15);
            int k0 = s * 32 + ((l >> 4) << 3);
            const float* src = Wsrc + (size_t)row * stride + k0;
            short v[8];
            #pragma unroll
            for (int j = 0; j < 8; ++j) v[j] = f2bf(src[j]);
            short* d = dst + ((size_t)fid * 64 + l) * 8;
            #pragma unroll
            for (int j = 0; j < 8; ++j) d[j] = v[j];
        } else {  // wscore + barrier zero
            int j = (n - 4096) * 256 + tid;
            wscore[j] = W_ih[(size_t)j * (D + 1) + D];
            if (n == 4096 && tid < 64) bar[tid] = 0u;
        }
        return;
    }

    int ch = n & 15, b = n >> 4;
    int w = tid >> 6, lane = tid & 63;
    float4 aw[4], acc[4];
    #pragma unroll
    for (int r = 0; r < 4; ++r) {
        aw[r] = *reinterpret_cast<const float4*>(&a_w[r * 256 + lane * 4]);
        acc[r] = make_float4(0.f, 0.f, 0.f, 0.f);
    }
    float m = -INFINITY, l = 0.f;
    const float* fb = feat + ((size_t)b * S + ch * 64 + w * 16) * D;
    for (int i = 0; i < 16; ++i) {
        float4 f[4];
        #pragma unroll
        for (int r = 0; r < 4; ++r)
            f[r] = *reinterpret_cast<const float4*>(&fb[(size_t)i * D + r * 256 + lane * 4]);
        float dot = 0.f;
        #pragma unroll
        for (int r = 0; r < 4; ++r)
            dot += f[r].x * aw[r].x + f[r].y * aw[r].y + f[r].z * aw[r].z + f[r].w * aw[r].w;
        dot = wave_sum_bc(dot);
        if (dot <= m) {
            float wg = expf(dot - m);
            l += wg;
            #pragma unroll
            for (int r = 0; r < 4; ++r) {
                acc[r].x += wg * f[r].x; acc[r].y += wg * f[r].y;
                acc[r].z += wg * f[r].z; acc[r].w += wg * f[r].w;
            }
        } else {
            float sc = expf(m - dot);
            l = l * sc + 1.f;
            #pragma unroll
            for (int r = 0; r < 4; ++r) {
                acc[r].x = acc[r].x * sc + f[r].x; acc[r].y = acc[r].y * sc + f[r].y;
                acc[r].z = acc[r].z * sc + f[r].z; acc[r].w = acc[r].w * sc + f[r].w;
            }
            m = dot;
        }
    }
    #pragma unroll
    for (int r = 0; r < 4; ++r)
        *reinterpret_cast<float4*>(&sacc[w][r * 256 + lane * 4]) = acc[r];
    if (lane == 0) { sml[w][0] = m; sml[w][1] = l; }
    __syncthreads();
    float m0 = sml[0][0], m1 = sml[1][0], m2 = sml[2][0], m3 = sml[3][0];
    float mg = fmaxf(fmaxf(m0, m1), fmaxf(m2, m3));
    float s0 = expf(m0 - mg), s1 = expf(m1 - mg), s2 = expf(m2 - mg), s3 = expf(m3 - mg);
    int c = tid * 4;
    float4 a0 = *reinterpret_cast<float4*>(&sacc[0][c]);
    float4 a1 = *reinterpret_cast<float4*>(&sacc[1][c]);
    float4 a2 = *reinterpret_cast<float4*>(&sacc[2][c]);
    float4 a3 = *reinterpret_cast<float4*>(&sacc[3][c]);
    float4 o;
    o.x = s0 * a0.x + s1 * a1.x + s2 * a2.x + s3 * a3.x;
    o.y = s0 * a0.y + s1 * a1.y + s2 * a2.y + s3 * a3.y;
    o.z = s0 * a0.z + s1 * a1.z + s2 * a2.z + s3 * a3.z;
    o.w = s0 * a0.w + s1 * a1.w + s2 * a2.w + s3 * a3.w;
    *reinterpret_cast<float4*>(&part[((size_t)b * 16 + ch) * D + c]) = o;
    if (tid == 0) {
        float lg = s0 * sml[0][1] + s1 * sml[1][1] + s2 * sml[2][1] + s3 * sml[3][1];
        ml[(b * 16 + ch) * 2] = mg;
        ml[(b * 16 + ch) * 2 + 1] = lg;
    }
}

// ---------------------------------------------------------------------------
// k_mid: pool-combine + pack A-fragments. 64 blocks.
__global__ __launch_bounds__(256) void k_mid(const float* __restrict__ part,
        const float* __restrict__ ml, short* __restrict__ pooledP) {
    int b = blockIdx.x, tid = threadIdx.x;
    float mg = -INFINITY;
    #pragma unroll
    for (int q = 0; q < 16; ++q) mg = fmaxf(mg, ml[(b * 16 + q) * 2]);
    float denom = 0.f, sc[16];
    #pragma unroll
    for (int q = 0; q < 16; ++q) {
        sc[q] = expf(ml[(b * 16 + q) * 2] - mg);
        denom += sc[q] * ml[(b * 16 + q) * 2 + 1];
    }
    float inv = 1.f / denom;
    int c = tid * 4;
    float4 o = make_float4(0.f, 0.f, 0.f, 0.f);
    #pragma unroll
    for (int q = 0; q < 16; ++q) {
        float4 p = *reinterpret_cast<const float4*>(&part[((size_t)b * 16 + q) * D + c]);
        o.x += sc[q] * p.x; o.y += sc[q] * p.y; o.z += sc[q] * p.z; o.w += sc[q] * p.w;
    }
    float ov[4] = {o.x * inv, o.y * inv, o.z * inv, o.w * inv};
    int m = b >> 4;
    #pragma unroll
    for (int j4 = 0; j4 < 4; ++j4) {
        int d = c + j4;
        int s = d >> 5, lane2 = (b & 15) + (((d >> 3) & 3) << 4), jj = d & 7;
        pooledP[(((size_t)m * 32 + s) * 64 + lane2) * 8 + jj] = f2bf(ov[j4]);
    }
}

// ---------------------------------------------------------------------------
// k_persist: step0 + 9 GRU steps + final, fence-free per-bh barriers.
// Grid 256 = (dt 0..63)x(bh 0..3) XCD-pinned, block 512 = 8 waves (k-eighths).
// Cross-block data (hp, spart) via agent-scope relaxed atomics (L3-coherent).
// Block-local state (gi, h) lives in LDS for the whole kernel.
__global__ __launch_bounds__(512, 2) void k_persist(const s8v* __restrict__ BihP,
        const s8v* __restrict__ BhhP, const short* __restrict__ pooledP,
        u64* hpA, u64* hpB, const float* __restrict__ wscore,
        const float* __restrict__ b_ih, const float* __restrict__ b_hh,
        const float* __restrict__ W_out, const float* __restrict__ b_out,
        float* spart, float* __restrict__ out, unsigned* bar) {
    __shared__ float psum[8][16][49];
    __shared__ float gilds[16][49];
    __shared__ float hl[16][17];
    __shared__ float sredS[16][17];
    __shared__ float sredO[16][17];
    __shared__ unsigned short hbf[16][16];

    int tid = threadIdx.x, w = tid >> 6, l = tid & 63;
    int n = blockIdx.x, xcd = n & 7, slot = n >> 3;
    int dt = xcd * 8 + (slot & 7), bh = slot >> 3;
    int bq0 = bh * 16;
    int lb = tid & 15, c = (tid >> 4) & 15;
    bool epi = (tid < 256);
    int b = bq0 + lb, d = dt * 16 + c;
    unsigned* cnt = &bar[bh * 16];

    // epilogue constants -> registers (once)
    float e_bo = b_out[0];
    float e_b0 = 0.f, e_b1 = 0.f, e_b2 = 0.f, e_wo = 0.f;
    float e_w0 = 0.f, e_w1 = 0.f, e_w2 = 0.f;
    if (epi) {
        e_b0 = b_hh[d]; e_b1 = b_hh[D + d]; e_b2 = b_hh[2 * D + d];
        e_wo = W_out[d];
        e_w0 = wscore[d]; e_w1 = wscore[D + d]; e_w2 = wscore[2 * D + d];
    }

    // W_hh B-fragments -> registers (reused 9 steps)
    s8v Bw[4][3];
    #pragma unroll
    for (int s8 = 0; s8 < 4; ++s8) {
        int s = w * 4 + s8;
        #pragma unroll
        for (int g = 0; g < 3; ++g)
            Bw[s8][g] = BhhP[((size_t)(dt * 3 + g) * 32 + s) * 64 + l];
    }

    // ---- step 0: A = pooledP, B = W_ih; gi kept in LDS ----
    {
        const s8v* Ap = reinterpret_cast<const s8v*>(pooledP);
        f4v acc[3];
        #pragma unroll
        for (int g = 0; g < 3; ++g) acc[g] = (f4v){0.f, 0.f, 0.f, 0.f};
        #pragma unroll
        for (int s8 = 0; s8 < 4; ++s8) {
            int s = w * 4 + s8;
            s8v a = Ap[((size_t)bh * 32 + s) * 64 + l];
            #pragma unroll
            for (int g = 0; g < 3; ++g) {
                s8v bb = BihP[((size_t)(dt * 3 + g) * 32 + s) * 64 + l];
                acc[g] = __builtin_amdgcn_mfma_f32_16x16x32_bf16(a, bb, acc[g], 0, 0, 0);
            }
        }
        #pragma unroll
        for (int g = 0; g < 3; ++g)
            #pragma unroll
            for (int r = 0; r < 4; ++r)
                psum[w][(l >> 4) * 4 + r][g * 16 + (l & 15)] = acc[g][r];
        __syncthreads();
        if (epi) {
            float g3[3];
            #pragma unroll
            for (int g = 0; g < 3; ++g) {
                float v = 0.f;
                #pragma unroll
                for (int ww = 0; ww < 8; ++ww) v += psum[ww][lb][g * 16 + c];
                g3[g] = v;
            }
            float gir = g3[0] + b_ih[d];
            float giz = g3[1] + b_ih[D + d];
            float gin = g3[2] + b_ih[2 * D + d];
            gilds[lb][c] = gir; gilds[lb][16 + c] = giz; gilds[lb][32 + c] = gin;
            float rr = sigm(gir + e_b0);
            float zz = sigm(giz + e_b1);
            float nn = tanhf(gin + rr * e_b2);
            float hnew = (1.f - zz) * nn;  // hprev = 0
            hl[lb][c] = hnew;
            hbf[lb][c] = (unsigned short)f2bf(hnew);
            sredO[lb][c] = hnew * e_wo;
        }
        __syncthreads();
        if (tid < 64) {  // pack h -> hpA fragments (agent-scope stores)
            int lb2 = tid & 15, k4 = tid >> 4;
            u64 v = (u64)hbf[lb2][k4 * 4] | ((u64)hbf[lb2][k4 * 4 + 1] << 16) |
                    ((u64)hbf[lb2][k4 * 4 + 2] << 32) | ((u64)hbf[lb2][k4 * 4 + 3] << 48);
            int q2 = (2 * dt + (k4 >> 1)) & 3;
            int lane2 = lb2 + (q2 << 4);
            size_t idx = (((size_t)bh * 32 + (dt >> 1)) * 64 + lane2) * 2 + (k4 & 1);
            astore64(&hpA[idx], v);
        }
        if (tid < 16) {
            float v = 0.f;
            #pragma unroll
            for (int q = 0; q < 16; ++q) v += sredO[tid][q];
            astoref(&spart[((size_t)0 * B + bq0 + tid) * 64 + dt], v);
        }
        __syncthreads();  // drains all waves' vmcnt before arrival
        if (tid == 0)
            __hip_atomic_fetch_add(cnt, 1u, __ATOMIC_RELAXED, __HIP_MEMORY_SCOPE_AGENT);
    }

    // ---- steps 1..9 ----
    for (int t = 1; t < C; ++t) {
        if (tid == 0) {
            unsigned tgt = (unsigned)(t * 64);
            while (__hip_atomic_load(cnt, __ATOMIC_RELAXED, __HIP_MEMORY_SCOPE_AGENT) < tgt)
                __builtin_amdgcn_s_sleep(4);
        }
        __syncthreads();
        if (epi) {  // pre-reduce previous scores (agent loads, hide under MFMA)
            float* sp = &spart[((size_t)(t - 1) * B + b) * 64 + c * 4];
            sredS[lb][c] = aloadf(sp) + aloadf(sp + 1) + aloadf(sp + 2) + aloadf(sp + 3);
        }
        u64* Ain = (t & 1) ? hpA : hpB;
        u64* Aout = (t & 1) ? hpB : hpA;
        f4v acc[3];
        #pragma unroll
        for (int g = 0; g < 3; ++g) acc[g] = (f4v){0.f, 0.f, 0.f, 0.f};
        #pragma unroll
        for (int s8 = 0; s8 < 4; ++s8) {
            int s = w * 4 + s8;
            size_t base = (((size_t)bh * 32 + s) * 64 + l) * 2;
            union { u64 q[2]; s8v v; } au;
            au.q[0] = aload64(&Ain[base]);
            au.q[1] = aload64(&Ain[base + 1]);
            #pragma unroll
            for (int g = 0; g < 3; ++g)
                acc[g] = __builtin_amdgcn_mfma_f32_16x16x32_bf16(au.v, Bw[s8][g], acc[g], 0, 0, 0);
        }
        #pragma unroll
        for (int g = 0; g < 3; ++g)
            #pragma unroll
            for (int r = 0; r < 4; ++r)
                psum[w][(l >> 4) * 4 + r][g * 16 + (l & 15)] = acc[g][r];
        __syncthreads();
        if (epi) {
            float g3[3];
            #pragma unroll
            for (int g = 0; g < 3; ++g) {
                float v = 0.f;
                #pragma unroll
                for (int ww = 0; ww < 8; ++ww) v += psum[ww][lb][g * 16 + c];
                g3[g] = v;
            }
            float ssum = e_bo;
            #pragma unroll
            for (int q = 0; q < 16; ++q) ssum += sredS[lb][q];
            float score = sigm(ssum);
            if (dt == 0 && c == 0) out[b * C + (t - 1)] = score;
            float gir = gilds[lb][c]      + score * e_w0;
            float giz = gilds[lb][16 + c] + score * e_w1;
            float gin = gilds[lb][32 + c] + score * e_w2;
            float rr = sigm(gir + e_b0 + g3[0]);
            float zz = sigm(giz + e_b1 + g3[1]);
            float nn = tanhf(gin + e_b2 + g3[2] + rr * (0.f) + rr * g3[2] * 0.f + 0.f);  // placeholder fixed below
            // NOTE: correct form computed explicitly:
            nn = tanhf(gin + rr * (e_b2 + g3[2]));
            float hnew = (1.f - zz) * nn + zz * hl[lb][c];
            hl[lb][c] = hnew;
            hbf[lb][c] = (unsigned short)f2bf(hnew);
            sredO[lb][c] = hnew * e_wo;
        }
        __syncthreads();
        if (tid < 64) {
            int lb2 = tid & 15, k4 = tid >> 4;
            u64 v = (u64)hbf[lb2][k4 * 4] | ((u64)hbf[lb2][k4 * 4 + 1] << 16) |
                    ((u64)hbf[lb2][k4 * 4 + 2] << 32) | ((u64)hbf[lb2][k4 * 4 + 3] << 48);
            int q2 = (2 * dt + (k4 >> 1)) & 3;
            int lane2 = lb2 + (q2 << 4);
            size_t idx = (((size_t)bh * 32 + (dt >> 1)) * 64 + lane2) * 2 + (k4 & 1);
            astore64(&Aout[idx], v);
        }
        if (tid < 16) {
            float v = 0.f;
            #pragma unroll
            for (int q = 0; q < 16; ++q) v += sredO[tid][q];
            astoref(&spart[((size_t)t * B + bq0 + tid) * 64 + dt], v);
        }
        __syncthreads();
        if (tid == 0)
            __hip_atomic_fetch_add(cnt, 1u, __ATOMIC_RELAXED, __HIP_MEMORY_SCOPE_AGENT);
    }

    // ---- final: out[:, C-1] by dt==0 blocks ----
    if (dt == 0) {
        if (tid == 0) {
            unsigned tgt = (unsigned)(C * 64);
            while (__hip_atomic_load(cnt, __ATOMIC_RELAXED, __HIP_MEMORY_SCOPE_AGENT) < tgt)
                __builtin_amdgcn_s_sleep(4);
        }
        __syncthreads();
        if (tid < 16) {
            int bb = bq0 + tid;
            float s = e_bo;
            for (int k = 0; k < 64; ++k)
                s += aloadf(&spart[((size_t)(C - 1) * B + bb) * 64 + k]);
            out[bb * C + (C - 1)] = sigm(s);
        }
    }
}

extern "C" void kernel_launch(void* const* d_in, const int* in_sizes, int n_in,
                              void* d_out, int out_size, void* d_ws, size_t ws_size,
                              hipStream_t stream) {
    const float* feat  = (const float*)d_in[0];
    const float* a_w   = (const float*)d_in[1];
    const float* W_ih  = (const float*)d_in[2];
    const float* W_hh  = (const float*)d_in[3];
    const float* b_ih  = (const float*)d_in[4];
    const float* b_hh  = (const float*)d_in[5];
    const float* W_out = (const float*)d_in[6];
    const float* b_out = (const float*)d_in[7];
    float* out = (float*)d_out;
    float* ws = (float*)d_ws;

    float* part    = ws;                           // B*16*D f
    float* ml      = part + (size_t)B * 16 * D;    // B*16*2 f
    float* spart   = ml + B * 16 * 2;              // C*B*64 f
    float* wscore  = spart + (size_t)C * B * 64;   // TD f
    short* pooledP = (short*)(wscore + TD);        // B*D sh
    short* hpA     = pooledP + (size_t)B * D;      // B*D sh
    short* hpB     = hpA + (size_t)B * D;          // B*D sh
    short* BihP    = hpB + (size_t)B * D;          // D*TD sh
    short* BhhP    = BihP + (size_t)D * TD;        // D*TD sh
    unsigned* bar  = (unsigned*)(BhhP + (size_t)D * TD);  // 64 u32

    k_pre<<<dim3(4108), 256, 0, stream>>>(feat, a_w, W_ih, W_hh, part, ml,
                                          BihP, BhhP, wscore, bar);
    k_mid<<<dim3(64), 256, 0, stream>>>(part, ml, pooledP);
    k_persist<<<dim3(256), 512, 0, stream>>>((const s8v*)BihP, (const s8v*)BhhP,
                                             pooledP, (u64*)hpA, (u64*)hpB,
                                             wscore, b_ih, b_hh, W_out, b_out,
                                             spart, out, bar);
}

// Round 9
// 110.922 us; speedup vs baseline: 5.8141x; 1.0090x over previous
//
#include <hip/hip_runtime.h>
#include <hip/hip_bf16.h>
#include <math.h>

#define B 64
#define S 1024
#define D 1024
#define C 10
#define TD 3072  // 3*D

typedef __attribute__((ext_vector_type(8))) short s8v;   // 8 bf16 (A/B frag)
typedef __attribute__((ext_vector_type(4))) float f4v;   // 4 f32  (C/D frag)
typedef unsigned long long u64;

__device__ __forceinline__ float wave_sum_bc(float v) {
    #pragma unroll
    for (int off = 1; off < 64; off <<= 1) v += __shfl_xor(v, off, 64);
    return v;
}
__device__ __forceinline__ float sigm(float x) { return 1.0f / (1.0f + expf(-x)); }
__device__ __forceinline__ short f2bf(float f) {
    __hip_bfloat16 h = __float2bfloat16(f);
    return *reinterpret_cast<short*>(&h);
}
// Agent-scope relaxed atomics: routed to L3, immune to stale per-XCD L2.
__device__ __forceinline__ u64 aload64(u64* p) {
    return __hip_atomic_load(p, __ATOMIC_RELAXED, __HIP_MEMORY_SCOPE_AGENT);
}
__device__ __forceinline__ void astore64(u64* p, u64 v) {
    __hip_atomic_store(p, v, __ATOMIC_RELAXED, __HIP_MEMORY_SCOPE_AGENT);
}
__device__ __forceinline__ void astoref(float* p, float v) {
    __hip_atomic_store(p, v, __ATOMIC_RELAXED, __HIP_MEMORY_SCOPE_AGENT);
}
// Per-wave poll: lane 0 spins; compiler fence stops hoisting of later loads.
__device__ __forceinline__ void wave_poll(unsigned* cnt, unsigned tgt, int l) {
    if (l == 0) {
        while (__hip_atomic_load(cnt, __ATOMIC_RELAXED, __HIP_MEMORY_SCOPE_AGENT) < tgt)
            __builtin_amdgcn_s_sleep(1);
    }
    asm volatile("" ::: "memory");
}

// ---------------------------------------------------------------------------
// k_pre: merged prologue (pooling partials + W packs + wscore + bar zero).
__global__ __launch_bounds__(256) void k_pre(const float* __restrict__ feat,
        const float* __restrict__ a_w, const float* __restrict__ W_ih,
        const float* __restrict__ W_hh, float* __restrict__ part, float* __restrict__ ml,
        short* __restrict__ BihP, short* __restrict__ BhhP, float* __restrict__ wscore,
        unsigned* __restrict__ bar) {
    __shared__ float sacc[4][1024];
    __shared__ float sml[4][2];
    int n = blockIdx.x, tid = threadIdx.x;

    if (n >= 1024) {
        if (n < 4096) {  // pack W
            int rel = n - 1024;
            const float* Wsrc = (rel < 1536) ? W_ih : W_hh;
            short* dst = (rel < 1536) ? BihP : BhhP;
            int stride = (rel < 1536) ? (D + 1) : D;
            int rn = (rel < 1536) ? rel : rel - 1536;
            int gid = rn * 256 + tid;
            int fid = gid >> 6, l = gid & 63;
            int s = fid & 31, g = (fid >> 5) % 3, dt = fid / 96;
            int row = g * 1024 + dt * 16 + (l & 15);
            int k0 = s * 32 + ((l >> 4) << 3);
            const float* src = Wsrc + (size_t)row * stride + k0;
            short v[8];
            #pragma unroll
            for (int j = 0; j < 8; ++j) v[j] = f2bf(src[j]);
            short* d = dst + ((size_t)fid * 64 + l) * 8;
            #pragma unroll
            for (int j = 0; j < 8; ++j) d[j] = v[j];
        } else {  // wscore + barrier zero
            int j = (n - 4096) * 256 + tid;
            wscore[j] = W_ih[(size_t)j * (D + 1) + D];
            if (n == 4096) {
                #pragma unroll
                for (int q = 0; q < 5; ++q) bar[q * 256 + tid] = 0u;
            }
        }
        return;
    }

    int ch = n & 15, b = n >> 4;
    int w = tid >> 6, lane = tid & 63;
    float4 aw[4], acc[4];
    #pragma unroll
    for (int r = 0; r < 4; ++r) {
        aw[r] = *reinterpret_cast<const float4*>(&a_w[r * 256 + lane * 4]);
        acc[r] = make_float4(0.f, 0.f, 0.f, 0.f);
    }
    float m = -INFINITY, l = 0.f;
    const float* fb = feat + ((size_t)b * S + ch * 64 + w * 16) * D;
    for (int i = 0; i < 16; ++i) {
        float4 f[4];
        #pragma unroll
        for (int r = 0; r < 4; ++r)
            f[r] = *reinterpret_cast<const float4*>(&fb[(size_t)i * D + r * 256 + lane * 4]);
        float dot = 0.f;
        #pragma unroll
        for (int r = 0; r < 4; ++r)
            dot += f[r].x * aw[r].x + f[r].y * aw[r].y + f[r].z * aw[r].z + f[r].w * aw[r].w;
        dot = wave_sum_bc(dot);
        if (dot <= m) {
            float wg = expf(dot - m);
            l += wg;
            #pragma unroll
            for (int r = 0; r < 4; ++r) {
                acc[r].x += wg * f[r].x; acc[r].y += wg * f[r].y;
                acc[r].z += wg * f[r].z; acc[r].w += wg * f[r].w;
            }
        } else {
            float sc = expf(m - dot);
            l = l * sc + 1.f;
            #pragma unroll
            for (int r = 0; r < 4; ++r) {
                acc[r].x = acc[r].x * sc + f[r].x; acc[r].y = acc[r].y * sc + f[r].y;
                acc[r].z = acc[r].z * sc + f[r].z; acc[r].w = acc[r].w * sc + f[r].w;
            }
            m = dot;
        }
    }
    #pragma unroll
    for (int r = 0; r < 4; ++r)
        *reinterpret_cast<float4*>(&sacc[w][r * 256 + lane * 4]) = acc[r];
    if (lane == 0) { sml[w][0] = m; sml[w][1] = l; }
    __syncthreads();
    float m0 = sml[0][0], m1 = sml[1][0], m2 = sml[2][0], m3 = sml[3][0];
    float mg = fmaxf(fmaxf(m0, m1), fmaxf(m2, m3));
    float s0 = expf(m0 - mg), s1 = expf(m1 - mg), s2 = expf(m2 - mg), s3 = expf(m3 - mg);
    int c = tid * 4;
    float4 a0 = *reinterpret_cast<float4*>(&sacc[0][c]);
    float4 a1 = *reinterpret_cast<float4*>(&sacc[1][c]);
    float4 a2 = *reinterpret_cast<float4*>(&sacc[2][c]);
    float4 a3 = *reinterpret_cast<float4*>(&sacc[3][c]);
    float4 o;
    o.x = s0 * a0.x + s1 * a1.x + s2 * a2.x + s3 * a3.x;
    o.y = s0 * a0.y + s1 * a1.y + s2 * a2.y + s3 * a3.y;
    o.z = s0 * a0.z + s1 * a1.z + s2 * a2.z + s3 * a3.z;
    o.w = s0 * a0.w + s1 * a1.w + s2 * a2.w + s3 * a3.w;
    *reinterpret_cast<float4*>(&part[((size_t)b * 16 + ch) * D + c]) = o;
    if (tid == 0) {
        float lg = s0 * sml[0][1] + s1 * sml[1][1] + s2 * sml[2][1] + s3 * sml[3][1];
        ml[(b * 16 + ch) * 2] = mg;
        ml[(b * 16 + ch) * 2 + 1] = lg;
    }
}

// ---------------------------------------------------------------------------
// k_persist: pool-combine + step0 + 9 GRU steps + final.
// Grid 256 = (dt 0..63)x(bh 0..3) XCD-pinned, block 512 = 8 waves (k-eighths).
// Per-eighth counters: wave w waits only for the 8 producer blocks of its
// k-range. Cross-block data via agent-scope relaxed atomics (L3-coherent).
__global__ __launch_bounds__(512, 2) void k_persist(const s8v* __restrict__ BihP,
        const s8v* __restrict__ BhhP, short* pooledP,
        u64* hpA, u64* hpB, const float* __restrict__ wscore,
        const float* __restrict__ b_ih, const float* __restrict__ b_hh,
        const float* __restrict__ W_out, const float* __restrict__ b_out,
        const float* __restrict__ part, const float* __restrict__ ml,
        float* spart, float* __restrict__ out, unsigned* bar) {
    __shared__ float psum[8][16][49];
    __shared__ float gilds[16][49];
    __shared__ float hl[16][17];
    __shared__ float sredS2[16][33];
    __shared__ float sredO[16][17];
    __shared__ unsigned short hbf[16][16];

    int tid = threadIdx.x, w = tid >> 6, l = tid & 63;
    int n = blockIdx.x, xcd = n & 7, slot = n >> 3;
    int dt = xcd * 8 + (slot & 7), bh = slot >> 3;
    int bq0 = bh * 16;
    int lb = tid & 15, c = (tid >> 4) & 15, c8 = tid >> 4;  // c8 0..31
    bool epi = (tid < 256);
    int b = bq0 + lb, d = dt * 16 + c;
    unsigned* cnt8 = &bar[(bh * 8) * 32];        // cnt8[e] at bar[(bh*8+e)*32]
    unsigned* cnt_pool = &bar[1024];
    u64* poolU = (u64*)pooledP;

    // ---- Phase A: pool-combine (blocks 0..63), u64 agent stores ----
    if (n < 64 && tid < 256) {
        int bb = n;
        float mg = -INFINITY;
        #pragma unroll
        for (int q = 0; q < 16; ++q) mg = fmaxf(mg, ml[(bb * 16 + q) * 2]);
        float denom = 0.f, sc[16];
        #pragma unroll
        for (int q = 0; q < 16; ++q) {
            sc[q] = expf(ml[(bb * 16 + q) * 2] - mg);
            denom += sc[q] * ml[(bb * 16 + q) * 2 + 1];
        }
        float inv = 1.f / denom;
        int cc = tid * 4;
        float4 o = make_float4(0.f, 0.f, 0.f, 0.f);
        #pragma unroll
        for (int q = 0; q < 16; ++q) {
            float4 p = *reinterpret_cast<const float4*>(&part[((size_t)bb * 16 + q) * D + cc]);
            o.x += sc[q] * p.x; o.y += sc[q] * p.y; o.z += sc[q] * p.z; o.w += sc[q] * p.w;
        }
        u64 v = (u64)(unsigned short)f2bf(o.x * inv) |
                ((u64)(unsigned short)f2bf(o.y * inv) << 16) |
                ((u64)(unsigned short)f2bf(o.z * inv) << 32) |
                ((u64)(unsigned short)f2bf(o.w * inv) << 48);
        int lane2 = (bb & 15) + (((cc >> 3) & 3) << 4);
        size_t idx = (((size_t)(bb >> 4) * 32 + (cc >> 5)) * 64 + lane2) * 2 + ((cc >> 2) & 1);
        astore64(&poolU[idx], v);
    }
    if (n < 64) {
        __syncthreads();  // drain combine stores (vmcnt) for all waves
        if (tid == 0) {
            asm volatile("s_waitcnt vmcnt(0)" ::: "memory");
            __hip_atomic_fetch_add(cnt_pool, 1u, __ATOMIC_RELAXED, __HIP_MEMORY_SCOPE_AGENT);
        }
    }

    // ---- Preload constants + W_hh fragments (overlaps pool wait) ----
    float e_bo = b_out[0];
    float e_b0 = 0.f, e_b1 = 0.f, e_b2 = 0.f, e_wo = 0.f;
    float e_w0 = 0.f, e_w1 = 0.f, e_w2 = 0.f, e_i0 = 0.f, e_i1 = 0.f, e_i2 = 0.f;
    if (epi) {
        e_b0 = b_hh[d]; e_b1 = b_hh[D + d]; e_b2 = b_hh[2 * D + d];
        e_wo = W_out[d];
        e_w0 = wscore[d]; e_w1 = wscore[D + d]; e_w2 = wscore[2 * D + d];
        e_i0 = b_ih[d]; e_i1 = b_ih[D + d]; e_i2 = b_ih[2 * D + d];
    }
    s8v Bw[4][3];
    #pragma unroll
    for (int s8 = 0; s8 < 4; ++s8) {
        int s = w * 4 + s8;
        #pragma unroll
        for (int g = 0; g < 3; ++g)
            Bw[s8][g] = BhhP[((size_t)(dt * 3 + g) * 32 + s) * 64 + l];
    }

    // ---- wait for pooled ----
    if (tid == 0) {
        while (__hip_atomic_load(cnt_pool, __ATOMIC_RELAXED, __HIP_MEMORY_SCOPE_AGENT) < 64u)
            __builtin_amdgcn_s_sleep(1);
    }
    __syncthreads();

    // ---- step 0: A = pooledP (aload64), B = W_ih ----
    {
        f4v acc[3];
        #pragma unroll
        for (int g = 0; g < 3; ++g) acc[g] = (f4v){0.f, 0.f, 0.f, 0.f};
        #pragma unroll
        for (int s8 = 0; s8 < 4; ++s8) {
            int s = w * 4 + s8;
            size_t base = (((size_t)bh * 32 + s) * 64 + l) * 2;
            union { u64 q[2]; s8v v; } au;
            au.q[0] = aload64(&poolU[base]);
            au.q[1] = aload64(&poolU[base + 1]);
            #pragma unroll
            for (int g = 0; g < 3; ++g) {
                s8v bb2 = BihP[((size_t)(dt * 3 + g) * 32 + s) * 64 + l];
                acc[g] = __builtin_amdgcn_mfma_f32_16x16x32_bf16(au.v, bb2, acc[g], 0, 0, 0);
            }
        }
        #pragma unroll
        for (int g = 0; g < 3; ++g)
            #pragma unroll
            for (int r = 0; r < 4; ++r)
                psum[w][(l >> 4) * 4 + r][g * 16 + (l & 15)] = acc[g][r];
        __syncthreads();
        if (epi) {
            float g3[3];
            #pragma unroll
            for (int g = 0; g < 3; ++g) {
                float v = 0.f;
                #pragma unroll
                for (int ww = 0; ww < 8; ++ww) v += psum[ww][lb][g * 16 + c];
                g3[g] = v;
            }
            float gir = g3[0] + e_i0, giz = g3[1] + e_i1, gin = g3[2] + e_i2;
            gilds[lb][c] = gir; gilds[lb][16 + c] = giz; gilds[lb][32 + c] = gin;
            float rr = sigm(gir + e_b0);
            float zz = sigm(giz + e_b1);
            float nn = tanhf(gin + rr * e_b2);
            float hnew = (1.f - zz) * nn;  // hprev = 0
            hl[lb][c] = hnew;
            hbf[lb][c] = (unsigned short)f2bf(hnew);
            sredO[lb][c] = hnew * e_wo;
        }
        __syncthreads();
        if (tid < 64) {
            int lb2 = tid & 15, k4 = tid >> 4;
            u64 v = (u64)hbf[lb2][k4 * 4] | ((u64)hbf[lb2][k4 * 4 + 1] << 16) |
                    ((u64)hbf[lb2][k4 * 4 + 2] << 32) | ((u64)hbf[lb2][k4 * 4 + 3] << 48);
            int q2 = (2 * dt + (k4 >> 1)) & 3;
            int lane2 = lb2 + (q2 << 4);
            astore64(&hpA[(((size_t)bh * 32 + (dt >> 1)) * 64 + lane2) * 2 + (k4 & 1)], v);
            if (tid < 16) {
                float v2 = 0.f;
                #pragma unroll
                for (int q = 0; q < 16; ++q) v2 += sredO[tid][q];
                astoref(&spart[((size_t)0 * B + bq0 + tid) * 64 + dt], v2);
            }
            asm volatile("s_waitcnt vmcnt(0)" ::: "memory");
            if (tid == 0)
                __hip_atomic_fetch_add(&cnt8[(dt >> 3) * 32], 1u, __ATOMIC_RELAXED,
                                       __HIP_MEMORY_SCOPE_AGENT);
        }
    }

    // ---- steps 1..9: per-wave eighth-granular barrier ----
    for (int t = 1; t < C; ++t) {
        wave_poll(&cnt8[w * 32], (unsigned)(t * 8), l);
        // spart pair for this wave's dt-eighth (c8*2, c8*2+1)
        {
            union { u64 q; float f[2]; } sv;
            sv.q = aload64(&((u64*)spart)[((size_t)(t - 1) * B + b) * 32 + c8]);
            sredS2[lb][c8] = sv.f[0] + sv.f[1];
        }
        u64* Ain = (t & 1) ? hpA : hpB;
        u64* Aout = (t & 1) ? hpB : hpA;
        f4v acc[3];
        #pragma unroll
        for (int g = 0; g < 3; ++g) acc[g] = (f4v){0.f, 0.f, 0.f, 0.f};
        #pragma unroll
        for (int s8 = 0; s8 < 4; ++s8) {
            int s = w * 4 + s8;
            size_t base = (((size_t)bh * 32 + s) * 64 + l) * 2;
            union { u64 q[2]; s8v v; } au;
            au.q[0] = aload64(&Ain[base]);
            au.q[1] = aload64(&Ain[base + 1]);
            #pragma unroll
            for (int g = 0; g < 3; ++g)
                acc[g] = __builtin_amdgcn_mfma_f32_16x16x32_bf16(au.v, Bw[s8][g], acc[g], 0, 0, 0);
        }
        #pragma unroll
        for (int g = 0; g < 3; ++g)
            #pragma unroll
            for (int r = 0; r < 4; ++r)
                psum[w][(l >> 4) * 4 + r][g * 16 + (l & 15)] = acc[g][r];
        __syncthreads();
        if (epi) {
            float g3[3];
            #pragma unroll
            for (int g = 0; g < 3; ++g) {
                float v = 0.f;
                #pragma unroll
                for (int ww = 0; ww < 8; ++ww) v += psum[ww][lb][g * 16 + c];
                g3[g] = v;
            }
            float ssum = e_bo;
            #pragma unroll
            for (int q = 0; q < 32; ++q) ssum += sredS2[lb][q];
            float score = sigm(ssum);
            if (dt == 0 && c == 0) out[b * C + (t - 1)] = score;
            float gir = gilds[lb][c]      + score * e_w0;
            float giz = gilds[lb][16 + c] + score * e_w1;
            float gin = gilds[lb][32 + c] + score * e_w2;
            float rr = sigm(gir + e_b0 + g3[0]);
            float zz = sigm(giz + e_b1 + g3[1]);
            float nn = tanhf(gin + rr * (e_b2 + g3[2]));
            float hnew = (1.f - zz) * nn + zz * hl[lb][c];
            hl[lb][c] = hnew;
            hbf[lb][c] = (unsigned short)f2bf(hnew);
            sredO[lb][c] = hnew * e_wo;
        }
        __syncthreads();
        if (tid < 64) {  // wave 0 only: stores + drain + arrival
            int lb2 = tid & 15, k4 = tid >> 4;
            u64 v = (u64)hbf[lb2][k4 * 4] | ((u64)hbf[lb2][k4 * 4 + 1] << 16) |
                    ((u64)hbf[lb2][k4 * 4 + 2] << 32) | ((u64)hbf[lb2][k4 * 4 + 3] << 48);
            int q2 = (2 * dt + (k4 >> 1)) & 3;
            int lane2 = lb2 + (q2 << 4);
            astore64(&Aout[(((size_t)bh * 32 + (dt >> 1)) * 64 + lane2) * 2 + (k4 & 1)], v);
            if (tid < 16) {
                float v2 = 0.f;
                #pragma unroll
                for (int q = 0; q < 16; ++q) v2 += sredO[tid][q];
                astoref(&spart[((size_t)t * B + bq0 + tid) * 64 + dt], v2);
            }
            asm volatile("s_waitcnt vmcnt(0)" ::: "memory");
            if (tid == 0)
                __hip_atomic_fetch_add(&cnt8[(dt >> 3) * 32], 1u, __ATOMIC_RELAXED,
                                       __HIP_MEMORY_SCOPE_AGENT);
        }
    }

    // ---- final: out[:, C-1] by dt==0 blocks ----
    if (dt == 0) {
        wave_poll(&cnt8[w * 32], (unsigned)(C * 8), l);
        __syncthreads();
        if (tid < 16) {
            int bb = bq0 + tid;
            float s = e_bo;
            for (int k = 0; k < 64; ++k) {
                float pv = __hip_atomic_load(&spart[((size_t)(C - 1) * B + bb) * 64 + k],
                                             __ATOMIC_RELAXED, __HIP_MEMORY_SCOPE_AGENT);
                s += pv;
            }
            out[bb * C + (C - 1)] = sigm(s);
        }
    }
}

extern "C" void kernel_launch(void* const* d_in, const int* in_sizes, int n_in,
                              void* d_out, int out_size, void* d_ws, size_t ws_size,
                              hipStream_t stream) {
    const float* feat  = (const float*)d_in[0];
    const float* a_w   = (const float*)d_in[1];
    const float* W_ih  = (const float*)d_in[2];
    const float* W_hh  = (const float*)d_in[3];
    const float* b_ih  = (const float*)d_in[4];
    const float* b_hh  = (const float*)d_in[5];
    const float* W_out = (const float*)d_in[6];
    const float* b_out = (const float*)d_in[7];
    float* out = (float*)d_out;
    float* ws = (float*)d_ws;

    float* part    = ws;                           // B*16*D f
    float* ml      = part + (size_t)B * 16 * D;    // B*16*2 f
    float* spart   = ml + B * 16 * 2;              // C*B*64 f
    float* wscore  = spart + (size_t)C * B * 64;   // TD f
    short* pooledP = (short*)(wscore + TD);        // B*D sh
    short* hpA     = pooledP + (size_t)B * D;      // B*D sh
    short* hpB     = hpA + (size_t)B * D;          // B*D sh
    short* BihP    = hpB + (size_t)B * D;          // D*TD sh
    short* BhhP    = BihP + (size_t)D * TD;        // D*TD sh
    unsigned* bar  = (unsigned*)(BhhP + (size_t)D * TD);  // 1280 u32

    k_pre<<<dim3(4108), 256, 0, stream>>>(feat, a_w, W_ih, W_hh, part, ml,
                                          BihP, BhhP, wscore, bar);
    k_persist<<<dim3(256), 512, 0, stream>>>((const s8v*)BihP, (const s8v*)BhhP,
                                             pooledP, (u64*)hpA, (u64*)hpB,
                                             wscore, b_ih, b_hh, W_out, b_out,
                                             part, ml, spart, out, bar);
}